// Round 9
// baseline (953.799 us; speedup 1.0000x reference)
//
#include <hip/hip_runtime.h>
#include <cstdint>
#include <cstddef>

#define IMG 512
#define JD 192

__device__ inline float fast_rcp(float x) { return __builtin_amdgcn_rcpf(x); }

// ---------------------------------------------------------------------------
// K1: partial Gram. grid (4 chunks, 4 slabs, 16 batches), 512 thr.
// Two 256-thread groups split the 32-patch nl range; 6x6 tiles; float2 LDS.
// ---------------------------------------------------------------------------
__global__ __launch_bounds__(512) void k_gram(const float* __restrict__ x,
                                              float* __restrict__ part) {
  const int ck = blockIdx.x;
  const int sl = blockIdx.y;
  const int b  = blockIdx.z;
  const int t  = threadIdx.x;
  __shared__ float tile[32][JD];
  __shared__ float pacc[256*37];   // group-1 partial accumulators
  const int g   = t >> 8;          // 0 or 1
  const int tid = t & 255;
  const int ty = tid >> 5;
  const int tx = tid & 31;
  const int r0 = sl*48 + ty*6;
  const int c0 = tx*6;
  float acc[6][6];
#pragma unroll
  for (int i=0;i<6;i++)
#pragma unroll
    for (int j=0;j<6;j++) acc[i][j]=0.f;
  const float* xb = x + (size_t)b*3*IMG*IMG;
  const int nbeg = ck*1024;
  const int nlo = g*16, nhi = nlo+16;
  for (int n0 = nbeg; n0 < nbeg+1024; n0 += 32) {
    for (int f = t; f < 32*JD; f += 512) {
      const int nl = f / JD, j = f - nl*JD;
      const int n = n0 + nl;
      const int hh = n >> 6, ww = n & 63;
      const int c = j >> 6, p = (j >> 3) & 7, q = j & 7;
      tile[nl][j] = xb[(c*IMG + hh*8+p)*IMG + ww*8 + q];
    }
    __syncthreads();
#pragma unroll 4
    for (int nl = nlo; nl < nhi; nl++) {
      const float2 a01 = *(const float2*)(&tile[nl][r0]);
      const float2 a23 = *(const float2*)(&tile[nl][r0+2]);
      const float2 a45 = *(const float2*)(&tile[nl][r0+4]);
      const float2 b01 = *(const float2*)(&tile[nl][c0]);
      const float2 b23 = *(const float2*)(&tile[nl][c0+2]);
      const float2 b45 = *(const float2*)(&tile[nl][c0+4]);
      const float va[6] = {a01.x,a01.y,a23.x,a23.y,a45.x,a45.y};
      const float vb[6] = {b01.x,b01.y,b23.x,b23.y,b45.x,b45.y};
#pragma unroll
      for (int i=0;i<6;i++)
#pragma unroll
        for (int j=0;j<6;j++) acc[i][j] += va[i]*vb[j];
    }
    __syncthreads();
  }
  // combine the two nl-halves
  if (g == 1) {
#pragma unroll
    for (int i=0;i<6;i++)
#pragma unroll
      for (int j=0;j<6;j++) pacc[tid*37 + i*6+j] = acc[i][j];
  }
  __syncthreads();
  if (g == 0) {
    float* dst = part + (((size_t)(b*4 + sl))*4 + ck) * (size_t)(48*JD);
#pragma unroll
    for (int i=0;i<6;i++)
#pragma unroll
      for (int j=0;j<6;j++)
        dst[(ty*6+i)*JD + c0+j] = acc[i][j] + pacc[tid*37 + i*6+j];
  }
}

// ---------------------------------------------------------------------------
// K2: reduce 4 chunk-partials -> Gs = G / 4096
// ---------------------------------------------------------------------------
__global__ __launch_bounds__(256) void k_greduce(const float* __restrict__ part,
                                                 float* __restrict__ Gs) {
  const int idx = blockIdx.x*256 + threadIdx.x;
  const int b = idx / (JD*JD);
  const int e = idx - b*(JD*JD);
  const int r = e / JD;
  const int sl = r / 48;
  const int w = (r - sl*48)*JD + (e - r*JD);
  const float* p = part + ((size_t)(b*4+sl))*4*(48*JD) + w;
  float s = 0.f;
#pragma unroll
  for (int ck=0; ck<4; ck++) s += p[(size_t)ck*48*JD];
  Gs[idx] = s * (1.0f/4096.0f);
}

// ---------------------------------------------------------------------------
// K3: D = S*S for symmetric S (per batch), lower-tri tile pairs. 256 thr.
// ---------------------------------------------------------------------------
__global__ __launch_bounds__(256) void k_sq(const float* __restrict__ S,
                                            float* __restrict__ D) {
  const int tp = blockIdx.x;
  const int b  = blockIdx.y;
  int ti, tj;
  if      (tp==0){ti=0;tj=0;} else if (tp==1){ti=1;tj=0;}
  else if (tp==2){ti=1;tj=1;} else if (tp==3){ti=2;tj=0;}
  else if (tp==4){ti=2;tj=1;} else            {ti=2;tj=2;}
  const float* Sb = S + (size_t)b*JD*JD;
  float* Db = D + (size_t)b*JD*JD;
  __shared__ float Ar[64][33];
  __shared__ float Br[64][33];
  const int t = threadIdx.x;
  const int ty = t >> 4, tx = t & 15;
  float acc[4][4];
#pragma unroll
  for (int i=0;i<4;i++)
#pragma unroll
    for (int j=0;j<4;j++) acc[i][j]=0.f;
  for (int k0=0; k0<JD; k0+=32) {
    for (int f=t; f<2048; f+=256) {
      const int row = f >> 5, kk = f & 31;
      Ar[row][kk] = Sb[(ti*64+row)*JD + k0+kk];
      Br[row][kk] = Sb[(tj*64+row)*JD + k0+kk];
    }
    __syncthreads();
#pragma unroll 4
    for (int k=0;k<32;k++) {
      float va[4], vb[4];
#pragma unroll
      for (int i=0;i<4;i++) va[i] = Ar[ty*4+i][k];
#pragma unroll
      for (int j=0;j<4;j++) vb[j] = Br[tx*4+j][k];
#pragma unroll
      for (int i=0;i<4;i++)
#pragma unroll
        for (int j=0;j<4;j++) acc[i][j] += va[i]*vb[j];
    }
    __syncthreads();
  }
#pragma unroll
  for (int i=0;i<4;i++)
#pragma unroll
    for (int j=0;j<4;j++) {
      const int r = ti*64+ty*4+i, c = tj*64+tx*4+j;
      Db[r*JD+c] = acc[i][j];
      if (ti != tj) Db[c*JD+r] = acc[i][j];
    }
}

// ---------------------------------------------------------------------------
// LDS-resident helpers for k_subH (512 threads). W: 192 rows, stride 68.
// ---------------------------------------------------------------------------

// In-place ridge-CholQR of Wl (192x68 LDS). S1 is 64x68 LDS scratch. BD=512.
__device__ void orth_lds(float* __restrict__ Wl, float* __restrict__ S1,
                         float* __restrict__ rdv, float* __restrict__ pdv,
                         float* __restrict__ misc, int t, float ridge) {
  const int ty = t >> 5, tx = t & 31;   // 16x32 grid -> 4x2 outputs
  float acc[4][2];
#pragma unroll
  for (int i=0;i<4;i++)
#pragma unroll
    for (int j=0;j<2;j++) acc[i][j]=0.f;
  __syncthreads();
  // ---- Gram: S1 = W^T W ----
#pragma unroll 2
  for (int r=0; r<JD; r++) {
    const float4 va4 = *(const float4*)(Wl + r*68 + ty*4);
    const float2 vb2 = *(const float2*)(Wl + r*68 + tx*2);
    const float a4[4] = {va4.x, va4.y, va4.z, va4.w};
    const float b2[2] = {vb2.x, vb2.y};
#pragma unroll
    for (int i=0;i<4;i++)
#pragma unroll
      for (int j=0;j<2;j++) acc[i][j] += a4[i]*b2[j];
  }
#pragma unroll
  for (int i=0;i<4;i++)
#pragma unroll
    for (int j=0;j<2;j++)
      S1[(ty*4+i)*68 + tx*2+j] = acc[i][j];
  __syncthreads();
  // ---- ridge ----
  if (ridge > 0.f) {
    if (t < 64) {
      float d = S1[t*68+t];
#pragma unroll
      for (int o=1;o<64;o<<=1) d = fmaxf(d, __shfl_xor(d, o));
      if (t == 0) misc[0] = d * ridge;
    }
    __syncthreads();
    if (t < 64) S1[t*68+t] += misc[0];
    __syncthreads();
  }
  // ---- blocked Cholesky (LDL-form, panel = 16) ----
  for (int p=0; p<4; p++) {
    const int b16 = p*16;
    // phase A: diagonal 16x16 factor, single wave, no barriers
    if (t < 64) {
      for (int jj=0; jj<16; jj++) {
        const int j = b16 + jj;
        const float invd = fast_rcp(S1[j*68+j]);
        if (t == 0) pdv[jj] = invd;
        const int nit = (15-jj)*16;
        for (int f=t; f<nit; f+=64) {
          const int i = j+1 + (f>>4);
          const int k = j+1 + (f&15);
          if (k <= i)
            S1[i*68+k] -= S1[i*68+j]*S1[k*68+j]*invd;
        }
      }
    }
    __syncthreads();
    // phase B: panel rows below diag block, one thread per row (registers)
    const int rb = b16 + 16;
    if (t < 64 - rb) {
      const int r = rb + t;
      float pr[16];
      float4* prp = (float4*)pr;
      prp[0] = *(const float4*)(S1 + r*68 + b16);
      prp[1] = *(const float4*)(S1 + r*68 + b16 + 4);
      prp[2] = *(const float4*)(S1 + r*68 + b16 + 8);
      prp[3] = *(const float4*)(S1 + r*68 + b16 + 12);
#pragma unroll
      for (int c=1; c<16; c++) {
        float s = pr[c];
#pragma unroll
        for (int j=0; j<c; j++) s -= pr[j]*S1[(b16+c)*68 + b16+j]*pdv[j];
        pr[c] = s;
      }
      *(float4*)(S1 + r*68 + b16)      = prp[0];
      *(float4*)(S1 + r*68 + b16 + 4)  = prp[1];
      *(float4*)(S1 + r*68 + b16 + 8)  = prp[2];
      *(float4*)(S1 + r*68 + b16 + 12) = prp[3];
    }
    __syncthreads();
    // phase C: trailing rank-16 update, fully parallel (stride 512)
    for (int f=t; f<2304; f+=512) {
      const int i = rb + f/48;
      const int k = rb + (f - (f/48)*48);
      if (i < 64 && k < 64 && k <= i) {
        float s = S1[i*68+k];
#pragma unroll
        for (int jj=0; jj<16; jj++)
          s -= S1[i*68 + b16+jj]*S1[k*68 + b16+jj]*pdv[jj];
        S1[i*68+k] = s;
      }
    }
    __syncthreads();
  }
  // ---- scale columns, triangular solve in registers ----
  if (t < 64) rdv[t] = rsqrtf(S1[t*68+t]);
  __syncthreads();
  for (int f=t; f<4096; f+=512) {
    const int i = f>>6, k = f&63;
    if (k < i) S1[i*68+k] *= rdv[k];
  }
  __syncthreads();
  if (t < JD) {
    float w[64];
    float4* wp = (float4*)w;
#pragma unroll
    for (int c4=0;c4<16;c4++) wp[c4] = *(const float4*)(Wl + t*68 + c4*4);
#pragma unroll
    for (int c=0;c<64;c++) {
      float v = w[c];
#pragma unroll
      for (int k=0;k<c;k++) v -= w[k]*S1[c*68+k];
      w[c] = v * rdv[c];
    }
#pragma unroll
    for (int c4=0;c4<16;c4++) *(float4*)(Wl + t*68 + c4*4) = wp[c4];
  }
  __syncthreads();
}

// Wout(192x68 LDS) = G(192x192 global) * Win(192x68 LDS); Gt scratch. BD=512.
__device__ void mm_lds(const float* __restrict__ G, const float* __restrict__ Win,
                       float* __restrict__ Wout, float* __restrict__ Gt, int t) {
  const int rg = t >> 3;   // 0..63 -> rows rg*3..+2
  const int cg = t & 7;    // cols cg*8..+7
  float acc[3][8];
#pragma unroll
  for (int i=0;i<3;i++)
#pragma unroll
    for (int j=0;j<8;j++) acc[i][j]=0.f;
  for (int k0=0; k0<JD; k0+=32) {
    __syncthreads();
    for (int f=t; f<6144; f+=512) {
      const int r = f >> 5, kk = f & 31;
      Gt[kk*193 + r] = G[r*JD + k0 + kk];
    }
    __syncthreads();
#pragma unroll 2
    for (int k=0;k<32;k++) {
      const float a0 = Gt[k*193 + rg*3+0];
      const float a1 = Gt[k*193 + rg*3+1];
      const float a2 = Gt[k*193 + rg*3+2];
      const float* wr = Win + (k0+k)*68 + cg*8;
#pragma unroll
      for (int j4=0;j4<2;j4++) {
        const float4 b4 = *(const float4*)(wr + 4*j4);
        const float bb[4] = {b4.x, b4.y, b4.z, b4.w};
#pragma unroll
        for (int jj=0;jj<4;jj++) {
          acc[0][j4*4+jj] += a0*bb[jj];
          acc[1][j4*4+jj] += a1*bb[jj];
          acc[2][j4*4+jj] += a2*bb[jj];
        }
      }
    }
  }
  __syncthreads();
#pragma unroll
  for (int i=0;i<3;i++)
#pragma unroll
    for (int j=0;j<8;j++)
      Wout[(rg*3+i)*68 + cg*8 + j] = acc[i][j];
  __syncthreads();
}

// S1 = X^T * Y (both 192x68 LDS), dst stride ss. BD=512.
__device__ void hgemm_lds(const float* __restrict__ X, const float* __restrict__ Y,
                          float* __restrict__ S1, int ss, int t) {
  const int ty = t >> 5, tx = t & 31;
  float acc[4][2];
#pragma unroll
  for (int i=0;i<4;i++)
#pragma unroll
    for (int j=0;j<2;j++) acc[i][j]=0.f;
#pragma unroll 2
  for (int r=0; r<JD; r++) {
    const float4 va4 = *(const float4*)(X + r*68 + ty*4);
    const float2 vb2 = *(const float2*)(Y + r*68 + tx*2);
    const float a4[4] = {va4.x, va4.y, va4.z, va4.w};
    const float b2[2] = {vb2.x, vb2.y};
#pragma unroll
    for (int i=0;i<4;i++)
#pragma unroll
      for (int j=0;j<2;j++) acc[i][j] += a4[i]*b2[j];
  }
  __syncthreads();
#pragma unroll
  for (int i=0;i<4;i++)
#pragma unroll
    for (int j=0;j<2;j++)
      S1[(ty*4+i)*ss + tx*2+j] = acc[i][j];
  __syncthreads();
}

// ---------------------------------------------------------------------------
// K4a: subspace basis + H, all W traffic in LDS. grid 16, 512 thr.
// ---------------------------------------------------------------------------
__global__ __launch_bounds__(512) void k_subH(const float* __restrict__ G32g,
                                              const float* __restrict__ Gsg,
                                              float* __restrict__ WbG,
                                              float* __restrict__ Hgg) {
  const int b = blockIdx.x;
  const int t = threadIdx.x;
  __shared__ float W0l[192*68];
  __shared__ float W1l[192*68];
  __shared__ float scr[32*193];   // unions: S1 (64x68) / Gt (32x193) / H (64x65)
  __shared__ float rdv[64];
  __shared__ float pdv[16];
  __shared__ float misc[8];
  const float* Gb  = G32g + (size_t)b*JD*JD;
  const float* Gsb = Gsg  + (size_t)b*JD*JD;

  for (int f=t; f<JD*64; f+=512)
    W0l[(f>>6)*68 + (f&63)] = Gb[(f>>6)*JD + (f&63)];
  __syncthreads();

  orth_lds(W0l, scr, rdv, pdv, misc, t, 1e-6f);   // span-preserving (ridged)
  mm_lds(Gb, W0l, W1l, scr, t);                   // power +32
  orth_lds(W1l, scr, rdv, pdv, misc, t, 1e-6f);
  orth_lds(W1l, scr, rdv, pdv, misc, t, 0.f);     // CholQR2 clean pass

  // H = W^T Gs W  (T1 = Gs*W into W0l, then hgemm -> scr at stride 65)
  mm_lds(Gsb, W1l, W0l, scr, t);
  hgemm_lds(W1l, W0l, scr, 65, t);

  float* Wb = WbG + (size_t)b*JD*64;
  for (int f=t; f<JD*64; f+=512)
    Wb[f] = W1l[(f>>6)*68 + (f&63)];
  float* Hb = Hgg + (size_t)b*4160;
  for (int f=t; f<4160; f+=512) Hb[f] = scr[f];
}

// ---------------------------------------------------------------------------
// Householder tridiag of A (64x64, stride 65) in place (256-thread update).
// ---------------------------------------------------------------------------
__device__ void dev_tridiag(float* __restrict__ A, float* a, float* b2,
                            float* bsg, float* v0s, float* bts,
                            float* vvec, float* wvec, int t) {
  for (int j=0; j<=61; j++) {
    const int m = 63 - j;
    if (t < 64) {
      float xi = (t < m) ? A[j*65 + (j+1+t)] : 0.f;
      float nr = xi*xi;
#pragma unroll
      for (int o=1;o<64;o<<=1) nr += __shfl_xor(nr, o);
      const float sig = sqrtf(nr);
      const float alpha = __shfl(xi, 0);
      const float sgn = (alpha >= 0.f) ? 1.f : -1.f;
      const float v0 = alpha + sgn*sig;
      const float beta = (sig > 1e-20f) ? 1.0f/(sig*fabsf(v0)) : 0.f;
      if (t < m) vvec[t] = (t==0) ? v0 : xi;
      if (t == 0) {
        a[j] = A[j*65+j]; b2[j] = nr; bsg[j] = -sgn*sig;
        v0s[j] = v0; bts[j] = beta;
      }
      float pv = 0.f;
      if (t < m) {
        const float* row = A + (j+1+t)*65 + (j+1);
        for (int c=0;c<m;c++) pv += row[c]*vvec[c];
        pv *= beta;
      }
      float dp = (t<m) ? vvec[t]*pv : 0.f;
#pragma unroll
      for (int o=1;o<64;o<<=1) dp += __shfl_xor(dp, o);
      const float gamma = 0.5f*beta*dp;
      if (t < m) wvec[t] = pv - gamma*vvec[t];
    }
    __syncthreads();
    const int mm = m*m;
    for (int f=t; f<mm; f+=256) {
      const int r = f/m, c = f - r*m;
      A[(j+1+r)*65 + (j+1+c)] -= vvec[r]*wvec[c] + wvec[r]*vvec[c];
    }
    __syncthreads();
  }
  if (t == 0) {
    a[62] = A[62*65+62];
    a[63] = A[63*65+63];
    const float bb = A[62*65+63];
    b2[62] = bb*bb;
    bsg[62] = bb;
  }
  __syncthreads();
}

// Sturm count with fast reciprocal
__device__ inline int sturm_cnt_fast(const float* a, const float* b2, float sig) {
  float d = a[0] - sig;
  int n = (d < 0.f) ? 1 : 0;
#pragma unroll 8
  for (int i=1;i<64;i++) {
    const float dd = (fabsf(d) < 1e-20f) ? -1e-20f : d;
    d = (a[i]-sig) - b2[i-1]*fast_rcp(dd);
    n += (d < 0.f) ? 1 : 0;
  }
  return n;
}

__device__ inline float dguard(float d) {
  if (fabsf(d) < 1e-12f) return (d < 0.f) ? -1e-12f : 1e-12f;
  return d;
}

// ---------------------------------------------------------------------------
// K4b: tridiag + eigenvalues + twisted + CholQR32 + backtransform, fused
// (SH stays in LDS between tridiag and backtransform). grid 16, 256 thr.
// ---------------------------------------------------------------------------
__global__ __launch_bounds__(256) void k_eigv(const float* __restrict__ Hgg,
                                              float* __restrict__ VtG) {
  const int b = blockIdx.x;
  const int t = threadIdx.x;
  __shared__ float SH[4160];
  __shared__ float Vt[64*36];
  __shared__ float dpA[64*33];
  __shared__ float dmA[64*33];
  __shared__ float ps[8*33];
  __shared__ float wvred[32];
  __shared__ float rdv[64];
  __shared__ float a64[64];
  __shared__ float b2v[64];
  __shared__ float bsg[64];
  __shared__ float v0s[64];
  __shared__ float bts[64];
  __shared__ float vvec[64];
  __shared__ float wvec[64];
  __shared__ float lam[32];
  __shared__ float misc[8];
  const float* Hb = Hgg + (size_t)b*4160;
  for (int f=t; f<4160; f+=256) SH[f] = Hb[f];
  __syncthreads();

  // ---- tridiagonalize H in place (keeps reflectors in SH rows) ----
  dev_tridiag(SH, a64, b2v, bsg, v0s, bts, vvec, wvec, t);

  // ---- spectrum bounds (Gershgorin) ----
  if (t < 64) {
    const float bl = (t>0)  ? sqrtf(b2v[t-1]) : 0.f;
    const float br = (t<63) ? sqrtf(b2v[t])   : 0.f;
    float lo = a64[t] - bl - br, hi = a64[t] + bl + br;
#pragma unroll
    for (int o=1;o<64;o<<=1) {
      lo = fminf(lo, __shfl_xor(lo,o));
      hi = fmaxf(hi, __shfl_xor(hi,o));
    }
    if (t == 0) { misc[0] = lo - 1e-4f; misc[1] = hi + 1e-4f; }
  }
  __syncthreads();

  // ---- 9-section search: 8 probes/eig in parallel, 10 rounds ----
  {
    const int l = t >> 3, g = t & 7;
    const int r = 32 + l;
    float L = misc[0], H = misc[1];
    for (int it=0; it<10; it++) {
      const float mid = L + (H-L)*((float)(g+1)*(1.0f/9.0f));
      const int cnt = sturm_cnt_fast(a64, b2v, mid);
      float nL = L, nH = H;
#pragma unroll
      for (int k=0;k<8;k++) {
        const int ck = __shfl(cnt, k, 8);
        const float pk = L + (H-L)*((float)(k+1)*(1.0f/9.0f));
        if (ck <= r) nL = fmaxf(nL, pk); else nH = fminf(nH, pk);
      }
      L = nL; H = nH;
    }
    if (g == 0) lam[l] = 0.5f*(L+H);
  }
  __syncthreads();

  // ---- twisted-factorization inverse iteration (lane l = one eigvec) ----
  if (t < 32) {
    const int l = t;
    const float lm = lam[l];
    float d = dguard(a64[0] - lm);
    dpA[0*33+l] = d;
    for (int i=1;i<64;i++) {
      d = dguard((a64[i]-lm) - b2v[i-1]*fast_rcp(d));
      dpA[i*33+l] = d;
    }
    float e = dguard(a64[63] - lm);
    dmA[63*33+l] = e;
    for (int i=62;i>=0;i--) {
      e = dguard((a64[i]-lm) - b2v[i]*fast_rcp(e));
      dmA[i*33+l] = e;
    }
    int ks = 0; float gbest = 1e30f;
    for (int i=0;i<64;i++) {
      const float g = fabsf(dpA[i*33+l] + dmA[i*33+l] - (a64[i]-lm));
      if (g < gbest) { gbest = g; ks = i; }
    }
    Vt[ks*36+l] = 1.f;
    float z = 1.f;
    for (int i=ks-1;i>=0;i--) {
      z = -(bsg[i]*z) * fast_rcp(dpA[i*33+l]);
      z = fminf(fmaxf(z, -1e18f), 1e18f);
      Vt[i*36+l] = z;
    }
    z = 1.f;
    for (int i=ks+1;i<64;i++) {
      z = -(bsg[i-1]*z) * fast_rcp(dmA[i*33+l]);
      z = fminf(fmaxf(z, -1e18f), 1e18f);
      Vt[i*36+l] = z;
    }
    float nr2 = 0.f;
    for (int i=0;i<64;i++) { const float zz = Vt[i*36+l]; nr2 += zz*zz; }
    const float inv = rsqrtf(nr2);
    for (int i=0;i<64;i++) Vt[i*36+l] *= inv;
  }
  __syncthreads();

  // ---- CholQR-32 safety pass on Vt ----
  for (int f=t; f<1024; f+=256) {
    const int i = f>>5, j = f&31;
    float s = 0.f;
    for (int r=0;r<64;r++) s += Vt[r*36+i]*Vt[r*36+j];
    dpA[i*33+j] = s;
  }
  __syncthreads();
  if (t == 0) {
    float m = 0.f;
    for (int j=0;j<32;j++) m = fmaxf(m, dpA[j*33+j]);
    misc[2] = m * 1e-7f;
  }
  __syncthreads();
  if (t < 32) dpA[t*33+t] += misc[2];
  for (int j=0;j<31;j++) {
    __syncthreads();
    const float invd = fast_rcp(dpA[j*33+j]);
    for (int f=t; f<(31-j)*32; f+=256) {
      const int i = j+1 + (f>>5);
      const int k = f & 31;
      if (k > j && k <= i)
        dpA[i*33+k] -= dpA[i*33+j]*dpA[k*33+j]*invd;
    }
  }
  __syncthreads();
  if (t < 32) rdv[t] = rsqrtf(dpA[t*33+t]);
  __syncthreads();
  for (int f=t; f<1024; f+=256) {
    const int i = f>>5, k = f&31;
    if (k < i) dpA[i*33+k] *= rdv[k];
  }
  __syncthreads();
  if (t < 64) {
    float w[32];
#pragma unroll
    for (int c=0;c<32;c++) w[c] = Vt[t*36+c];
#pragma unroll
    for (int c=0;c<32;c++) {
      float v = w[c];
#pragma unroll
      for (int k=0;k<c;k++) v -= w[k]*dpA[c*33+k];
      w[c] = v * rdv[c];
    }
#pragma unroll
    for (int c=0;c<32;c++) Vt[t*36+c] = w[c];
  }
  __syncthreads();

  // ---- backtransform: V = H_0 H_1 ... H_61 Vt ----
  for (int j=61; j>=0; j--) {
    const int m = 63 - j;
    {
      const int c = t & 31, g = t >> 5;
      float s = 0.f;
      for (int r=g; r<m; r+=8) {
        const float vr = (r==0) ? v0s[j] : SH[j*65 + (j+1+r)];
        s += vr * Vt[(j+1+r)*36 + c];
      }
      ps[g*33+c] = s;
    }
    __syncthreads();
    if (t < 32) {
      float s = 0.f;
#pragma unroll
      for (int g=0;g<8;g++) s += ps[g*33+t];
      wvred[t] = s * bts[j];
    }
    __syncthreads();
    {
      const int c = t & 31, g = t >> 5;
      for (int r=g; r<m; r+=8) {
        const float vr = (r==0) ? v0s[j] : SH[j*65 + (j+1+r)];
        Vt[(j+1+r)*36 + c] -= vr * wvred[c];
      }
    }
    __syncthreads();
  }

  float* Vb = VtG + (size_t)b*2048;
  for (int f=t; f<2048; f+=256) Vb[f] = Vt[(f>>5)*36 + (f&31)];
}

// ---------------------------------------------------------------------------
// K4c: B^T = (W*V)^T -> Btg (32 x 192 row-major per batch). grid 16.
// ---------------------------------------------------------------------------
__global__ __launch_bounds__(256) void k_bv(const float* __restrict__ WbG,
                                            const float* __restrict__ VtG,
                                            float* __restrict__ Btg) {
  const int b = blockIdx.x;
  const int t = threadIdx.x;
  __shared__ float Vt[64*36];
  const float* W = WbG + (size_t)b*JD*64;
  const float* Vb = VtG + (size_t)b*2048;
  float* Bt = Btg + (size_t)b*32*JD;
  for (int f=t; f<2048; f+=256) Vt[(f>>5)*36 + (f&31)] = Vb[f];
  __syncthreads();
  if (t < JD) {
    float accv[32];
#pragma unroll
    for (int c=0;c<32;c++) accv[c] = 0.f;
    const float4* crow = (const float4*)(W + t*64);
#pragma unroll 2
    for (int kb=0; kb<16; kb++) {
      const float4 av = crow[kb];
      const float a4[4] = {av.x, av.y, av.z, av.w};
#pragma unroll
      for (int ki=0; ki<4; ki++) {
        const float aa = a4[ki];
        const float* vrow = Vt + (kb*4+ki)*36;
        const float4 v0 = *(const float4*)(vrow+0);
        const float4 v1 = *(const float4*)(vrow+4);
        const float4 v2 = *(const float4*)(vrow+8);
        const float4 v3 = *(const float4*)(vrow+12);
        const float4 v4 = *(const float4*)(vrow+16);
        const float4 v5 = *(const float4*)(vrow+20);
        const float4 v6 = *(const float4*)(vrow+24);
        const float4 v7 = *(const float4*)(vrow+28);
        accv[0]+=aa*v0.x; accv[1]+=aa*v0.y; accv[2]+=aa*v0.z; accv[3]+=aa*v0.w;
        accv[4]+=aa*v1.x; accv[5]+=aa*v1.y; accv[6]+=aa*v1.z; accv[7]+=aa*v1.w;
        accv[8]+=aa*v2.x; accv[9]+=aa*v2.y; accv[10]+=aa*v2.z; accv[11]+=aa*v2.w;
        accv[12]+=aa*v3.x; accv[13]+=aa*v3.y; accv[14]+=aa*v3.z; accv[15]+=aa*v3.w;
        accv[16]+=aa*v4.x; accv[17]+=aa*v4.y; accv[18]+=aa*v4.z; accv[19]+=aa*v4.w;
        accv[20]+=aa*v5.x; accv[21]+=aa*v5.y; accv[22]+=aa*v5.z; accv[23]+=aa*v5.w;
        accv[24]+=aa*v6.x; accv[25]+=aa*v6.y; accv[26]+=aa*v6.z; accv[27]+=aa*v6.w;
        accv[28]+=aa*v7.x; accv[29]+=aa*v7.y; accv[30]+=aa*v7.z; accv[31]+=aa*v7.w;
      }
    }
#pragma unroll
    for (int c=0;c<32;c++) Bt[c*JD + t] = accv[c];
  }
}

// ---------------------------------------------------------------------------
// K4d: M = B B^T = Bt^T Bt, lower-tri tile pairs. grid (6,16).
// ---------------------------------------------------------------------------
__global__ __launch_bounds__(256) void k_mm(const float* __restrict__ Btg,
                                            float* __restrict__ Mg) {
  const int tp = blockIdx.x;
  const int b  = blockIdx.y;
  int ti, tj;
  if      (tp==0){ti=0;tj=0;} else if (tp==1){ti=1;tj=0;}
  else if (tp==2){ti=1;tj=1;} else if (tp==3){ti=2;tj=0;}
  else if (tp==4){ti=2;tj=1;} else            {ti=2;tj=2;}
  const float* Bt = Btg + (size_t)b*32*JD;
  float* Mb = Mg + (size_t)b*JD*JD;
  __shared__ float Ar[32][68];
  __shared__ float Br[32][68];
  const int t = threadIdx.x;
  const int ty = t >> 4, tx = t & 15;
  for (int f=t; f<2048; f+=256) {
    const int k = f >> 6, c = f & 63;
    Ar[k][c] = Bt[k*JD + ti*64 + c];
    Br[k][c] = Bt[k*JD + tj*64 + c];
  }
  __syncthreads();
  float acc[4][4];
#pragma unroll
  for (int i=0;i<4;i++)
#pragma unroll
    for (int j=0;j<4;j++) acc[i][j]=0.f;
#pragma unroll 4
  for (int k=0;k<32;k++) {
    const float4 va4 = *(const float4*)(&Ar[k][ty*4]);
    const float4 vb4 = *(const float4*)(&Br[k][tx*4]);
    const float a4[4] = {va4.x, va4.y, va4.z, va4.w};
    const float b4[4] = {vb4.x, vb4.y, vb4.z, vb4.w};
#pragma unroll
    for (int i=0;i<4;i++)
#pragma unroll
      for (int j=0;j<4;j++) acc[i][j] += a4[i]*b4[j];
  }
#pragma unroll
  for (int i=0;i<4;i++)
#pragma unroll
    for (int j=0;j<4;j++) {
      const int r = ti*64+ty*4+i, c = tj*64+tx*4+j;
      Mb[r*JD+c] = acc[i][j];
      if (ti != tj) Mb[c*JD+r] = acc[i][j];
    }
}

// ---------------------------------------------------------------------------
// K5: recon = A * M, fused depatchify. grid (128 patch-blocks, 16 batches).
// ---------------------------------------------------------------------------
__global__ __launch_bounds__(256) void k_recon(const float* __restrict__ x,
                                               const float* __restrict__ Mg,
                                               float* __restrict__ out) {
  const int nb = blockIdx.x;
  const int b  = blockIdx.y;
  const int t  = threadIdx.x;
  __shared__ float At[32][17];
  __shared__ float Mt[16][JD];
  const float* xb = x + (size_t)b*3*IMG*IMG;
  const float* Mb = Mg + (size_t)b*JD*JD;
  float* ob = out + (size_t)b*3*IMG*IMG;
  const int pg = t >> 4;
  const int jg = t & 15;
  float acc[2][12];
#pragma unroll
  for (int i=0;i<2;i++)
#pragma unroll
    for (int j=0;j<12;j++) acc[i][j]=0.f;
  for (int j0=0; j0<JD; j0+=16) {
    for (int f=t; f<512; f+=256) {
      const int nl = f >> 4, jj = f & 15;
      const int j = j0 + jj;
      const int n = nb*32 + nl;
      const int hh = n >> 6, ww = n & 63;
      const int c = j >> 6, p = (j >> 3) & 7, q = j & 7;
      At[nl][jj] = xb[(c*IMG + hh*8+p)*IMG + ww*8 + q];
    }
    for (int f=t; f<768; f+=256) {
      const int jj = f/48, cc = (f - jj*48)*4;
      *(float4*)(&Mt[jj][cc]) = *(const float4*)(Mb + (size_t)(j0+jj)*JD + cc);
    }
    __syncthreads();
#pragma unroll 4
    for (int jj=0;jj<16;jj++) {
      const float a0 = At[pg*2+0][jj];
      const float a1 = At[pg*2+1][jj];
      const float4 m0 = *(const float4*)(&Mt[jj][jg*12]);
      const float4 m1 = *(const float4*)(&Mt[jj][jg*12+4]);
      const float4 m2 = *(const float4*)(&Mt[jj][jg*12+8]);
      const float mm[12] = {m0.x,m0.y,m0.z,m0.w,m1.x,m1.y,m1.z,m1.w,
                            m2.x,m2.y,m2.z,m2.w};
#pragma unroll
      for (int j=0;j<12;j++) {
        acc[0][j] += a0*mm[j];
        acc[1][j] += a1*mm[j];
      }
    }
    __syncthreads();
  }
#pragma unroll
  for (int i=0;i<2;i++) {
    const int n = nb*32 + pg*2 + i;
    const int hh = n >> 6, ww = n & 63;
#pragma unroll
    for (int j4=0;j4<3;j4++) {
      const int jo = jg*12 + j4*4;
      const int c = jo >> 6, p = (jo >> 3) & 7, q = jo & 7;
      const float4 v = make_float4(acc[i][j4*4+0], acc[i][j4*4+1],
                                   acc[i][j4*4+2], acc[i][j4*4+3]);
      *(float4*)(ob + (size_t)(c*IMG + hh*8+p)*IMG + ww*8 + q) = v;
    }
  }
}

// ---------------------------------------------------------------------------
extern "C" void kernel_launch(void* const* d_in, const int* in_sizes, int n_in,
                              void* d_out, int out_size, void* d_ws, size_t ws_size,
                              hipStream_t stream) {
  (void)in_sizes; (void)n_in; (void)out_size; (void)ws_size;
  const float* x = (const float*)d_in[0];
  float* out = (float*)d_out;
  float* ws  = (float*)d_ws;

  float* part = ws;                    // dead after k_greduce
  float* Gs   = ws + 2359296;
  float* P0   = ws + 2949120;
  float* P1   = ws + 3538944;
  // overlays on the (dead) part region:
  float* Mg   = ws;                    // 589824
  float* Wb   = ws + 786432;           // 196608
  float* Hg   = ws + 983040;           // 66560 (64x65 per batch)
  float* Vtg  = ws + 1057792;          // 32768
  float* Btg  = ws + 1090560;          // 98304 (32x192 per batch)

  k_gram  <<<dim3(4,4,16), 512, 0, stream>>>(x, part);
  k_greduce<<<2304,        256, 0, stream>>>(part, Gs);
  k_sq    <<<dim3(6,16),   256, 0, stream>>>(Gs, P0);   // Gs^2
  k_sq    <<<dim3(6,16),   256, 0, stream>>>(P0, P1);   // Gs^4
  k_sq    <<<dim3(6,16),   256, 0, stream>>>(P1, P0);   // Gs^8
  k_sq    <<<dim3(6,16),   256, 0, stream>>>(P0, P1);   // Gs^16
  k_sq    <<<dim3(6,16),   256, 0, stream>>>(P1, P0);   // Gs^32
  k_subH  <<<16,           512, 0, stream>>>(P0, Gs, Wb, Hg);
  k_eigv  <<<16,           256, 0, stream>>>(Hg, Vtg);
  k_bv    <<<16,           256, 0, stream>>>(Wb, Vtg, Btg);
  k_mm    <<<dim3(6,16),   256, 0, stream>>>(Btg, Mg);
  k_recon <<<dim3(128,16), 256, 0, stream>>>(x, Mg, out);
}

// Round 10
// 862.183 us; speedup vs baseline: 1.1063x; 1.1063x over previous
//
#include <hip/hip_runtime.h>
#include <cstdint>
#include <cstddef>

#define IMG 512
#define JD 192

__device__ inline float fast_rcp(float x) { return __builtin_amdgcn_rcpf(x); }

// ---------------------------------------------------------------------------
// K1: partial Gram. grid (4 chunks, 4 slabs, 16 batches), 512 thr.
// Two 256-thread groups split the 32-patch nl range; 6x6 tiles; float2 LDS
// reads; float4 global staging; double-buffered tile with issue-early /
// write-late split (one barrier per 32-patch step).
// ---------------------------------------------------------------------------
__global__ __launch_bounds__(512) void k_gram(const float* __restrict__ x,
                                              float* __restrict__ part) {
  const int ck = blockIdx.x;
  const int sl = blockIdx.y;
  const int b  = blockIdx.z;
  const int t  = threadIdx.x;
  __shared__ float tile[2][32][JD];    // 49.2 KB
  __shared__ float pacc[256*37];       // 37.9 KB (group-1 partials)
  const int g   = t >> 8;              // 0 or 1
  const int tid = t & 255;
  const int ty = tid >> 5;
  const int tx = tid & 31;
  const int r0 = sl*48 + ty*6;
  const int c0 = tx*6;
  float acc[6][6];
#pragma unroll
  for (int i=0;i<6;i++)
#pragma unroll
    for (int j=0;j<6;j++) acc[i][j]=0.f;
  const float* xb = x + (size_t)b*3*IMG*IMG;
  const int nbeg = ck*1024;
  const int nlo = g*16, nhi = nlo+16;

  // staging slots: f = t + 512k -> (nl, j4); global addr = cpo + hh*8*IMG + ww*8
  int snl[3]; size_t cpo[3]; float* wp0[3];
#pragma unroll
  for (int k=0;k<3;k++) {
    const int f = t + k*512;
    const int nl = f/48, j4 = f - nl*48;
    const int c = j4 >> 4, p = (j4 >> 1) & 7, q = (j4 & 1)*4;
    snl[k] = nl;
    cpo[k] = (size_t)(c*IMG + p)*IMG + q;
    wp0[k] = &tile[0][nl][j4*4];
  }
  float4 regs[3];
  // prologue: stage tile 0
#pragma unroll
  for (int k=0;k<3;k++) {
    const int n = nbeg + snl[k];
    regs[k] = *(const float4*)(xb + cpo[k] + (size_t)(n>>6)*8*IMG + (n&63)*8);
  }
#pragma unroll
  for (int k=0;k<3;k++) *(float4*)wp0[k] = regs[k];
  __syncthreads();

  int cur = 0;
  for (int it=0; it<32; it++) {
    if (it < 31) {                     // issue next-tile loads early
      const int n0 = nbeg + (it+1)*32;
#pragma unroll
      for (int k=0;k<3;k++) {
        const int n = n0 + snl[k];
        regs[k] = *(const float4*)(xb + cpo[k] + (size_t)(n>>6)*8*IMG + (n&63)*8);
      }
    }
    const float* tb = &tile[cur][0][0];
#pragma unroll 4
    for (int nl = nlo; nl < nhi; nl++) {
      const float* tr = tb + nl*JD;
      const float2 a01 = *(const float2*)(tr + r0);
      const float2 a23 = *(const float2*)(tr + r0+2);
      const float2 a45 = *(const float2*)(tr + r0+4);
      const float2 b01 = *(const float2*)(tr + c0);
      const float2 b23 = *(const float2*)(tr + c0+2);
      const float2 b45 = *(const float2*)(tr + c0+4);
      const float va[6] = {a01.x,a01.y,a23.x,a23.y,a45.x,a45.y};
      const float vb[6] = {b01.x,b01.y,b23.x,b23.y,b45.x,b45.y};
#pragma unroll
      for (int i=0;i<6;i++)
#pragma unroll
        for (int j=0;j<6;j++) acc[i][j] += va[i]*vb[j];
    }
    if (it < 31) {                     // write-late (vmcnt drained under compute)
#pragma unroll
      for (int k=0;k<3;k++) *(float4*)(wp0[k] + (cur^1)*6144) = regs[k];
    }
    __syncthreads();
    cur ^= 1;
  }
  // combine the two nl-halves
  if (g == 1) {
#pragma unroll
    for (int i=0;i<6;i++)
#pragma unroll
      for (int j=0;j<6;j++) pacc[tid*37 + i*6+j] = acc[i][j];
  }
  __syncthreads();
  if (g == 0) {
    float* dst = part + (((size_t)(b*4 + sl))*4 + ck) * (size_t)(48*JD);
#pragma unroll
    for (int i=0;i<6;i++)
#pragma unroll
      for (int j=0;j<6;j++)
        dst[(ty*6+i)*JD + c0+j] = acc[i][j] + pacc[tid*37 + i*6+j];
  }
}

// ---------------------------------------------------------------------------
// K2: reduce 4 chunk-partials -> Gs = G / 4096
// ---------------------------------------------------------------------------
__global__ __launch_bounds__(256) void k_greduce(const float* __restrict__ part,
                                                 float* __restrict__ Gs) {
  const int idx = blockIdx.x*256 + threadIdx.x;
  const int b = idx / (JD*JD);
  const int e = idx - b*(JD*JD);
  const int r = e / JD;
  const int sl = r / 48;
  const int w = (r - sl*48)*JD + (e - r*JD);
  const float* p = part + ((size_t)(b*4+sl))*4*(48*JD) + w;
  float s = 0.f;
#pragma unroll
  for (int ck=0; ck<4; ck++) s += p[(size_t)ck*48*JD];
  Gs[idx] = s * (1.0f/4096.0f);
}

// ---------------------------------------------------------------------------
// K3: D = S*S for symmetric S (per batch), lower-tri tile pairs. 256 thr.
// ---------------------------------------------------------------------------
__global__ __launch_bounds__(256) void k_sq(const float* __restrict__ S,
                                            float* __restrict__ D) {
  const int tp = blockIdx.x;
  const int b  = blockIdx.y;
  int ti, tj;
  if      (tp==0){ti=0;tj=0;} else if (tp==1){ti=1;tj=0;}
  else if (tp==2){ti=1;tj=1;} else if (tp==3){ti=2;tj=0;}
  else if (tp==4){ti=2;tj=1;} else            {ti=2;tj=2;}
  const float* Sb = S + (size_t)b*JD*JD;
  float* Db = D + (size_t)b*JD*JD;
  __shared__ float Ar[64][33];
  __shared__ float Br[64][33];
  const int t = threadIdx.x;
  const int ty = t >> 4, tx = t & 15;
  float acc[4][4];
#pragma unroll
  for (int i=0;i<4;i++)
#pragma unroll
    for (int j=0;j<4;j++) acc[i][j]=0.f;
  for (int k0=0; k0<JD; k0+=32) {
    for (int f=t; f<2048; f+=256) {
      const int row = f >> 5, kk = f & 31;
      Ar[row][kk] = Sb[(ti*64+row)*JD + k0+kk];
      Br[row][kk] = Sb[(tj*64+row)*JD + k0+kk];
    }
    __syncthreads();
#pragma unroll 4
    for (int k=0;k<32;k++) {
      float va[4], vb[4];
#pragma unroll
      for (int i=0;i<4;i++) va[i] = Ar[ty*4+i][k];
#pragma unroll
      for (int j=0;j<4;j++) vb[j] = Br[tx*4+j][k];
#pragma unroll
      for (int i=0;i<4;i++)
#pragma unroll
        for (int j=0;j<4;j++) acc[i][j] += va[i]*vb[j];
    }
    __syncthreads();
  }
#pragma unroll
  for (int i=0;i<4;i++)
#pragma unroll
    for (int j=0;j<4;j++) {
      const int r = ti*64+ty*4+i, c = tj*64+tx*4+j;
      Db[r*JD+c] = acc[i][j];
      if (ti != tj) Db[c*JD+r] = acc[i][j];
    }
}

// ---------------------------------------------------------------------------
// LDS-resident helpers for k_subH (512 threads). W: 192 rows, stride 68.
// ---------------------------------------------------------------------------

// In-place ridge-CholQR of Wl (192x68 LDS). S1 is 64x68 LDS scratch. BD=512.
__device__ void orth_lds(float* __restrict__ Wl, float* __restrict__ S1,
                         float* __restrict__ rdv, float* __restrict__ pdv,
                         float* __restrict__ misc, int t, float ridge) {
  const int ty = t >> 5, tx = t & 31;   // 16x32 grid -> 4x2 outputs
  float acc[4][2];
#pragma unroll
  for (int i=0;i<4;i++)
#pragma unroll
    for (int j=0;j<2;j++) acc[i][j]=0.f;
  __syncthreads();
  // ---- Gram: S1 = W^T W ----
#pragma unroll 2
  for (int r=0; r<JD; r++) {
    const float4 va4 = *(const float4*)(Wl + r*68 + ty*4);
    const float2 vb2 = *(const float2*)(Wl + r*68 + tx*2);
    const float a4[4] = {va4.x, va4.y, va4.z, va4.w};
    const float b2[2] = {vb2.x, vb2.y};
#pragma unroll
    for (int i=0;i<4;i++)
#pragma unroll
      for (int j=0;j<2;j++) acc[i][j] += a4[i]*b2[j];
  }
#pragma unroll
  for (int i=0;i<4;i++)
#pragma unroll
    for (int j=0;j<2;j++)
      S1[(ty*4+i)*68 + tx*2+j] = acc[i][j];
  __syncthreads();
  // ---- ridge ----
  if (ridge > 0.f) {
    if (t < 64) {
      float d = S1[t*68+t];
#pragma unroll
      for (int o=1;o<64;o<<=1) d = fmaxf(d, __shfl_xor(d, o));
      if (t == 0) misc[0] = d * ridge;
    }
    __syncthreads();
    if (t < 64) S1[t*68+t] += misc[0];
    __syncthreads();
  }
  // ---- blocked Cholesky (LDL-form, panel = 16) ----
  for (int p=0; p<4; p++) {
    const int b16 = p*16;
    // phase A: diagonal 16x16 factor, single wave, no barriers
    if (t < 64) {
      for (int jj=0; jj<16; jj++) {
        const int j = b16 + jj;
        const float invd = fast_rcp(S1[j*68+j]);
        if (t == 0) pdv[jj] = invd;
        const int nit = (15-jj)*16;
        for (int f=t; f<nit; f+=64) {
          const int i = j+1 + (f>>4);
          const int k = j+1 + (f&15);
          if (k <= i)
            S1[i*68+k] -= S1[i*68+j]*S1[k*68+j]*invd;
        }
      }
    }
    __syncthreads();
    // phase B: panel rows below diag block, one thread per row (registers)
    const int rb = b16 + 16;
    if (t < 64 - rb) {
      const int r = rb + t;
      float pr[16];
      float4* prp = (float4*)pr;
      prp[0] = *(const float4*)(S1 + r*68 + b16);
      prp[1] = *(const float4*)(S1 + r*68 + b16 + 4);
      prp[2] = *(const float4*)(S1 + r*68 + b16 + 8);
      prp[3] = *(const float4*)(S1 + r*68 + b16 + 12);
#pragma unroll
      for (int c=1; c<16; c++) {
        float s = pr[c];
#pragma unroll
        for (int j=0; j<c; j++) s -= pr[j]*S1[(b16+c)*68 + b16+j]*pdv[j];
        pr[c] = s;
      }
      *(float4*)(S1 + r*68 + b16)      = prp[0];
      *(float4*)(S1 + r*68 + b16 + 4)  = prp[1];
      *(float4*)(S1 + r*68 + b16 + 8)  = prp[2];
      *(float4*)(S1 + r*68 + b16 + 12) = prp[3];
    }
    __syncthreads();
    // phase C: trailing rank-16 update, fully parallel (stride 512)
    for (int f=t; f<2304; f+=512) {
      const int i = rb + f/48;
      const int k = rb + (f - (f/48)*48);
      if (i < 64 && k < 64 && k <= i) {
        float s = S1[i*68+k];
#pragma unroll
        for (int jj=0; jj<16; jj++)
          s -= S1[i*68 + b16+jj]*S1[k*68 + b16+jj]*pdv[jj];
        S1[i*68+k] = s;
      }
    }
    __syncthreads();
  }
  // ---- scale columns, triangular solve in registers ----
  if (t < 64) rdv[t] = rsqrtf(S1[t*68+t]);
  __syncthreads();
  for (int f=t; f<4096; f+=512) {
    const int i = f>>6, k = f&63;
    if (k < i) S1[i*68+k] *= rdv[k];
  }
  __syncthreads();
  if (t < JD) {
    float w[64];
    float4* wp = (float4*)w;
#pragma unroll
    for (int c4=0;c4<16;c4++) wp[c4] = *(const float4*)(Wl + t*68 + c4*4);
#pragma unroll
    for (int c=0;c<64;c++) {
      float v = w[c];
#pragma unroll
      for (int k=0;k<c;k++) v -= w[k]*S1[c*68+k];
      w[c] = v * rdv[c];
    }
#pragma unroll
    for (int c4=0;c4<16;c4++) *(float4*)(Wl + t*68 + c4*4) = wp[c4];
  }
  __syncthreads();
}

// Wout(192x68 LDS) = G(192x192 global) * Win(192x68 LDS); Gt scratch. BD=512.
__device__ void mm_lds(const float* __restrict__ G, const float* __restrict__ Win,
                       float* __restrict__ Wout, float* __restrict__ Gt, int t) {
  const int rg = t >> 3;   // 0..63 -> rows rg*3..+2
  const int cg = t & 7;    // cols cg*8..+7
  float acc[3][8];
#pragma unroll
  for (int i=0;i<3;i++)
#pragma unroll
    for (int j=0;j<8;j++) acc[i][j]=0.f;
  for (int k0=0; k0<JD; k0+=32) {
    __syncthreads();
    for (int f=t; f<6144; f+=512) {
      const int r = f >> 5, kk = f & 31;
      Gt[kk*193 + r] = G[r*JD + k0 + kk];
    }
    __syncthreads();
#pragma unroll 2
    for (int k=0;k<32;k++) {
      const float a0 = Gt[k*193 + rg*3+0];
      const float a1 = Gt[k*193 + rg*3+1];
      const float a2 = Gt[k*193 + rg*3+2];
      const float* wr = Win + (k0+k)*68 + cg*8;
#pragma unroll
      for (int j4=0;j4<2;j4++) {
        const float4 b4 = *(const float4*)(wr + 4*j4);
        const float bb[4] = {b4.x, b4.y, b4.z, b4.w};
#pragma unroll
        for (int jj=0;jj<4;jj++) {
          acc[0][j4*4+jj] += a0*bb[jj];
          acc[1][j4*4+jj] += a1*bb[jj];
          acc[2][j4*4+jj] += a2*bb[jj];
        }
      }
    }
  }
  __syncthreads();
#pragma unroll
  for (int i=0;i<3;i++)
#pragma unroll
    for (int j=0;j<8;j++)
      Wout[(rg*3+i)*68 + cg*8 + j] = acc[i][j];
  __syncthreads();
}

// S1 = X^T * Y (both 192x68 LDS), dst stride ss. BD=512.
__device__ void hgemm_lds(const float* __restrict__ X, const float* __restrict__ Y,
                          float* __restrict__ S1, int ss, int t) {
  const int ty = t >> 5, tx = t & 31;
  float acc[4][2];
#pragma unroll
  for (int i=0;i<4;i++)
#pragma unroll
    for (int j=0;j<2;j++) acc[i][j]=0.f;
#pragma unroll 2
  for (int r=0; r<JD; r++) {
    const float4 va4 = *(const float4*)(X + r*68 + ty*4);
    const float2 vb2 = *(const float2*)(Y + r*68 + tx*2);
    const float a4[4] = {va4.x, va4.y, va4.z, va4.w};
    const float b2[2] = {vb2.x, vb2.y};
#pragma unroll
    for (int i=0;i<4;i++)
#pragma unroll
      for (int j=0;j<2;j++) acc[i][j] += a4[i]*b2[j];
  }
  __syncthreads();
#pragma unroll
  for (int i=0;i<4;i++)
#pragma unroll
    for (int j=0;j<2;j++)
      S1[(ty*4+i)*ss + tx*2+j] = acc[i][j];
  __syncthreads();
}

// ---------------------------------------------------------------------------
// K4a: subspace basis + H, all W traffic in LDS. grid 16, 512 thr.
// ---------------------------------------------------------------------------
__global__ __launch_bounds__(512) void k_subH(const float* __restrict__ G32g,
                                              const float* __restrict__ Gsg,
                                              float* __restrict__ WbG,
                                              float* __restrict__ Hgg) {
  const int b = blockIdx.x;
  const int t = threadIdx.x;
  __shared__ float W0l[192*68];
  __shared__ float W1l[192*68];
  __shared__ float scr[32*193];   // unions: S1 (64x68) / Gt (32x193) / H (64x65)
  __shared__ float rdv[64];
  __shared__ float pdv[16];
  __shared__ float misc[8];
  const float* Gb  = G32g + (size_t)b*JD*JD;
  const float* Gsb = Gsg  + (size_t)b*JD*JD;

  for (int f=t; f<JD*64; f+=512)
    W0l[(f>>6)*68 + (f&63)] = Gb[(f>>6)*JD + (f&63)];
  __syncthreads();

  orth_lds(W0l, scr, rdv, pdv, misc, t, 1e-6f);   // span-preserving (ridged)
  mm_lds(Gb, W0l, W1l, scr, t);                   // power +32
  orth_lds(W1l, scr, rdv, pdv, misc, t, 1e-6f);
  orth_lds(W1l, scr, rdv, pdv, misc, t, 0.f);     // CholQR2 clean pass

  // H = W^T Gs W  (T1 = Gs*W into W0l, then hgemm -> scr at stride 65)
  mm_lds(Gsb, W1l, W0l, scr, t);
  hgemm_lds(W1l, W0l, scr, 65, t);

  float* Wb = WbG + (size_t)b*JD*64;
  for (int f=t; f<JD*64; f+=512)
    Wb[f] = W1l[(f>>6)*68 + (f&63)];
  float* Hb = Hgg + (size_t)b*4160;
  for (int f=t; f<4160; f+=512) Hb[f] = scr[f];
}

// ---------------------------------------------------------------------------
// Householder tridiag of A (64x64, stride 65) in place (256-thread update).
// ---------------------------------------------------------------------------
__device__ void dev_tridiag(float* __restrict__ A, float* a, float* b2,
                            float* bsg, float* v0s, float* bts,
                            float* vvec, float* wvec, int t) {
  for (int j=0; j<=61; j++) {
    const int m = 63 - j;
    if (t < 64) {
      float xi = (t < m) ? A[j*65 + (j+1+t)] : 0.f;
      float nr = xi*xi;
#pragma unroll
      for (int o=1;o<64;o<<=1) nr += __shfl_xor(nr, o);
      const float sig = sqrtf(nr);
      const float alpha = __shfl(xi, 0);
      const float sgn = (alpha >= 0.f) ? 1.f : -1.f;
      const float v0 = alpha + sgn*sig;
      const float beta = (sig > 1e-20f) ? 1.0f/(sig*fabsf(v0)) : 0.f;
      if (t < m) vvec[t] = (t==0) ? v0 : xi;
      if (t == 0) {
        a[j] = A[j*65+j]; b2[j] = nr; bsg[j] = -sgn*sig;
        v0s[j] = v0; bts[j] = beta;
      }
      float pv = 0.f;
      if (t < m) {
        const float* row = A + (j+1+t)*65 + (j+1);
        for (int c=0;c<m;c++) pv += row[c]*vvec[c];
        pv *= beta;
      }
      float dp = (t<m) ? vvec[t]*pv : 0.f;
#pragma unroll
      for (int o=1;o<64;o<<=1) dp += __shfl_xor(dp, o);
      const float gamma = 0.5f*beta*dp;
      if (t < m) wvec[t] = pv - gamma*vvec[t];
    }
    __syncthreads();
    const int mm = m*m;
    for (int f=t; f<mm; f+=256) {
      const int r = f/m, c = f - r*m;
      A[(j+1+r)*65 + (j+1+c)] -= vvec[r]*wvec[c] + wvec[r]*vvec[c];
    }
    __syncthreads();
  }
  if (t == 0) {
    a[62] = A[62*65+62];
    a[63] = A[63*65+63];
    const float bb = A[62*65+63];
    b2[62] = bb*bb;
    bsg[62] = bb;
  }
  __syncthreads();
}

// Sturm count with fast reciprocal
__device__ inline int sturm_cnt_fast(const float* a, const float* b2, float sig) {
  float d = a[0] - sig;
  int n = (d < 0.f) ? 1 : 0;
#pragma unroll 8
  for (int i=1;i<64;i++) {
    const float dd = (fabsf(d) < 1e-20f) ? -1e-20f : d;
    d = (a[i]-sig) - b2[i-1]*fast_rcp(dd);
    n += (d < 0.f) ? 1 : 0;
  }
  return n;
}

__device__ inline float dguard(float d) {
  if (fabsf(d) < 1e-12f) return (d < 0.f) ? -1e-12f : 1e-12f;
  return d;
}

// ---------------------------------------------------------------------------
// K4b: tridiag + eigenvalues + twisted + CholQR32 + backtransform, fused
// (SH stays in LDS between tridiag and backtransform). grid 16, 256 thr.
// ---------------------------------------------------------------------------
__global__ __launch_bounds__(256) void k_eigv(const float* __restrict__ Hgg,
                                              float* __restrict__ VtG) {
  const int b = blockIdx.x;
  const int t = threadIdx.x;
  __shared__ float SH[4160];
  __shared__ float Vt[64*36];
  __shared__ float dpA[64*33];
  __shared__ float dmA[64*33];
  __shared__ float ps[8*33];
  __shared__ float wvred[32];
  __shared__ float rdv[64];
  __shared__ float a64[64];
  __shared__ float b2v[64];
  __shared__ float bsg[64];
  __shared__ float v0s[64];
  __shared__ float bts[64];
  __shared__ float vvec[64];
  __shared__ float wvec[64];
  __shared__ float lam[32];
  __shared__ float misc[8];
  const float* Hb = Hgg + (size_t)b*4160;
  for (int f=t; f<4160; f+=256) SH[f] = Hb[f];
  __syncthreads();

  // ---- tridiagonalize H in place (keeps reflectors in SH rows) ----
  dev_tridiag(SH, a64, b2v, bsg, v0s, bts, vvec, wvec, t);

  // ---- spectrum bounds (Gershgorin) ----
  if (t < 64) {
    const float bl = (t>0)  ? sqrtf(b2v[t-1]) : 0.f;
    const float br = (t<63) ? sqrtf(b2v[t])   : 0.f;
    float lo = a64[t] - bl - br, hi = a64[t] + bl + br;
#pragma unroll
    for (int o=1;o<64;o<<=1) {
      lo = fminf(lo, __shfl_xor(lo,o));
      hi = fmaxf(hi, __shfl_xor(hi,o));
    }
    if (t == 0) { misc[0] = lo - 1e-4f; misc[1] = hi + 1e-4f; }
  }
  __syncthreads();

  // ---- 9-section search: 8 probes/eig in parallel, 10 rounds ----
  {
    const int l = t >> 3, g = t & 7;
    const int r = 32 + l;
    float L = misc[0], H = misc[1];
    for (int it=0; it<10; it++) {
      const float mid = L + (H-L)*((float)(g+1)*(1.0f/9.0f));
      const int cnt = sturm_cnt_fast(a64, b2v, mid);
      float nL = L, nH = H;
#pragma unroll
      for (int k=0;k<8;k++) {
        const int ck = __shfl(cnt, k, 8);
        const float pk = L + (H-L)*((float)(k+1)*(1.0f/9.0f));
        if (ck <= r) nL = fmaxf(nL, pk); else nH = fminf(nH, pk);
      }
      L = nL; H = nH;
    }
    if (g == 0) lam[l] = 0.5f*(L+H);
  }
  __syncthreads();

  // ---- twisted-factorization inverse iteration (lane l = one eigvec) ----
  if (t < 32) {
    const int l = t;
    const float lm = lam[l];
    float d = dguard(a64[0] - lm);
    dpA[0*33+l] = d;
    for (int i=1;i<64;i++) {
      d = dguard((a64[i]-lm) - b2v[i-1]*fast_rcp(d));
      dpA[i*33+l] = d;
    }
    float e = dguard(a64[63] - lm);
    dmA[63*33+l] = e;
    for (int i=62;i>=0;i--) {
      e = dguard((a64[i]-lm) - b2v[i]*fast_rcp(e));
      dmA[i*33+l] = e;
    }
    int ks = 0; float gbest = 1e30f;
    for (int i=0;i<64;i++) {
      const float g = fabsf(dpA[i*33+l] + dmA[i*33+l] - (a64[i]-lm));
      if (g < gbest) { gbest = g; ks = i; }
    }
    Vt[ks*36+l] = 1.f;
    float z = 1.f;
    for (int i=ks-1;i>=0;i--) {
      z = -(bsg[i]*z) * fast_rcp(dpA[i*33+l]);
      z = fminf(fmaxf(z, -1e18f), 1e18f);
      Vt[i*36+l] = z;
    }
    z = 1.f;
    for (int i=ks+1;i<64;i++) {
      z = -(bsg[i-1]*z) * fast_rcp(dmA[i*33+l]);
      z = fminf(fmaxf(z, -1e18f), 1e18f);
      Vt[i*36+l] = z;
    }
    float nr2 = 0.f;
    for (int i=0;i<64;i++) { const float zz = Vt[i*36+l]; nr2 += zz*zz; }
    const float inv = rsqrtf(nr2);
    for (int i=0;i<64;i++) Vt[i*36+l] *= inv;
  }
  __syncthreads();

  // ---- CholQR-32 safety pass on Vt ----
  for (int f=t; f<1024; f+=256) {
    const int i = f>>5, j = f&31;
    float s = 0.f;
    for (int r=0;r<64;r++) s += Vt[r*36+i]*Vt[r*36+j];
    dpA[i*33+j] = s;
  }
  __syncthreads();
  if (t == 0) {
    float m = 0.f;
    for (int j=0;j<32;j++) m = fmaxf(m, dpA[j*33+j]);
    misc[2] = m * 1e-7f;
  }
  __syncthreads();
  if (t < 32) dpA[t*33+t] += misc[2];
  for (int j=0;j<31;j++) {
    __syncthreads();
    const float invd = fast_rcp(dpA[j*33+j]);
    for (int f=t; f<(31-j)*32; f+=256) {
      const int i = j+1 + (f>>5);
      const int k = f & 31;
      if (k > j && k <= i)
        dpA[i*33+k] -= dpA[i*33+j]*dpA[k*33+j]*invd;
    }
  }
  __syncthreads();
  if (t < 32) rdv[t] = rsqrtf(dpA[t*33+t]);
  __syncthreads();
  for (int f=t; f<1024; f+=256) {
    const int i = f>>5, k = f&31;
    if (k < i) dpA[i*33+k] *= rdv[k];
  }
  __syncthreads();
  if (t < 64) {
    float w[32];
#pragma unroll
    for (int c=0;c<32;c++) w[c] = Vt[t*36+c];
#pragma unroll
    for (int c=0;c<32;c++) {
      float v = w[c];
#pragma unroll
      for (int k=0;k<c;k++) v -= w[k]*dpA[c*33+k];
      w[c] = v * rdv[c];
    }
#pragma unroll
    for (int c=0;c<32;c++) Vt[t*36+c] = w[c];
  }
  __syncthreads();

  // ---- backtransform: V = H_0 H_1 ... H_61 Vt ----
  for (int j=61; j>=0; j--) {
    const int m = 63 - j;
    {
      const int c = t & 31, g = t >> 5;
      float s = 0.f;
      for (int r=g; r<m; r+=8) {
        const float vr = (r==0) ? v0s[j] : SH[j*65 + (j+1+r)];
        s += vr * Vt[(j+1+r)*36 + c];
      }
      ps[g*33+c] = s;
    }
    __syncthreads();
    if (t < 32) {
      float s = 0.f;
#pragma unroll
      for (int g=0;g<8;g++) s += ps[g*33+t];
      wvred[t] = s * bts[j];
    }
    __syncthreads();
    {
      const int c = t & 31, g = t >> 5;
      for (int r=g; r<m; r+=8) {
        const float vr = (r==0) ? v0s[j] : SH[j*65 + (j+1+r)];
        Vt[(j+1+r)*36 + c] -= vr * wvred[c];
      }
    }
    __syncthreads();
  }

  float* Vb = VtG + (size_t)b*2048;
  for (int f=t; f<2048; f+=256) Vb[f] = Vt[(f>>5)*36 + (f&31)];
}

// ---------------------------------------------------------------------------
// K4c: B^T = (W*V)^T -> Btg (32 x 192 row-major per batch). grid 16.
// ---------------------------------------------------------------------------
__global__ __launch_bounds__(256) void k_bv(const float* __restrict__ WbG,
                                            const float* __restrict__ VtG,
                                            float* __restrict__ Btg) {
  const int b = blockIdx.x;
  const int t = threadIdx.x;
  __shared__ float Vt[64*36];
  const float* W = WbG + (size_t)b*JD*64;
  const float* Vb = VtG + (size_t)b*2048;
  float* Bt = Btg + (size_t)b*32*JD;
  for (int f=t; f<2048; f+=256) Vt[(f>>5)*36 + (f&31)] = Vb[f];
  __syncthreads();
  if (t < JD) {
    float accv[32];
#pragma unroll
    for (int c=0;c<32;c++) accv[c] = 0.f;
    const float4* crow = (const float4*)(W + t*64);
#pragma unroll 2
    for (int kb=0; kb<16; kb++) {
      const float4 av = crow[kb];
      const float a4[4] = {av.x, av.y, av.z, av.w};
#pragma unroll
      for (int ki=0; ki<4; ki++) {
        const float aa = a4[ki];
        const float* vrow = Vt + (kb*4+ki)*36;
        const float4 v0 = *(const float4*)(vrow+0);
        const float4 v1 = *(const float4*)(vrow+4);
        const float4 v2 = *(const float4*)(vrow+8);
        const float4 v3 = *(const float4*)(vrow+12);
        const float4 v4 = *(const float4*)(vrow+16);
        const float4 v5 = *(const float4*)(vrow+20);
        const float4 v6 = *(const float4*)(vrow+24);
        const float4 v7 = *(const float4*)(vrow+28);
        accv[0]+=aa*v0.x; accv[1]+=aa*v0.y; accv[2]+=aa*v0.z; accv[3]+=aa*v0.w;
        accv[4]+=aa*v1.x; accv[5]+=aa*v1.y; accv[6]+=aa*v1.z; accv[7]+=aa*v1.w;
        accv[8]+=aa*v2.x; accv[9]+=aa*v2.y; accv[10]+=aa*v2.z; accv[11]+=aa*v2.w;
        accv[12]+=aa*v3.x; accv[13]+=aa*v3.y; accv[14]+=aa*v3.z; accv[15]+=aa*v3.w;
        accv[16]+=aa*v4.x; accv[17]+=aa*v4.y; accv[18]+=aa*v4.z; accv[19]+=aa*v4.w;
        accv[20]+=aa*v5.x; accv[21]+=aa*v5.y; accv[22]+=aa*v5.z; accv[23]+=aa*v5.w;
        accv[24]+=aa*v6.x; accv[25]+=aa*v6.y; accv[26]+=aa*v6.z; accv[27]+=aa*v6.w;
        accv[28]+=aa*v7.x; accv[29]+=aa*v7.y; accv[30]+=aa*v7.z; accv[31]+=aa*v7.w;
      }
    }
#pragma unroll
    for (int c=0;c<32;c++) Bt[c*JD + t] = accv[c];
  }
}

// ---------------------------------------------------------------------------
// K4d: M = B B^T = Bt^T Bt, lower-tri tile pairs. grid (6,16).
// ---------------------------------------------------------------------------
__global__ __launch_bounds__(256) void k_mm(const float* __restrict__ Btg,
                                            float* __restrict__ Mg) {
  const int tp = blockIdx.x;
  const int b  = blockIdx.y;
  int ti, tj;
  if      (tp==0){ti=0;tj=0;} else if (tp==1){ti=1;tj=0;}
  else if (tp==2){ti=1;tj=1;} else if (tp==3){ti=2;tj=0;}
  else if (tp==4){ti=2;tj=1;} else            {ti=2;tj=2;}
  const float* Bt = Btg + (size_t)b*32*JD;
  float* Mb = Mg + (size_t)b*JD*JD;
  __shared__ float Ar[32][68];
  __shared__ float Br[32][68];
  const int t = threadIdx.x;
  const int ty = t >> 4, tx = t & 15;
  for (int f=t; f<2048; f+=256) {
    const int k = f >> 6, c = f & 63;
    Ar[k][c] = Bt[k*JD + ti*64 + c];
    Br[k][c] = Bt[k*JD + tj*64 + c];
  }
  __syncthreads();
  float acc[4][4];
#pragma unroll
  for (int i=0;i<4;i++)
#pragma unroll
    for (int j=0;j<4;j++) acc[i][j]=0.f;
#pragma unroll 4
  for (int k=0;k<32;k++) {
    const float4 va4 = *(const float4*)(&Ar[k][ty*4]);
    const float4 vb4 = *(const float4*)(&Br[k][tx*4]);
    const float a4[4] = {va4.x, va4.y, va4.z, va4.w};
    const float b4[4] = {vb4.x, vb4.y, vb4.z, vb4.w};
#pragma unroll
    for (int i=0;i<4;i++)
#pragma unroll
      for (int j=0;j<4;j++) acc[i][j] += a4[i]*b4[j];
  }
#pragma unroll
  for (int i=0;i<4;i++)
#pragma unroll
    for (int j=0;j<4;j++) {
      const int r = ti*64+ty*4+i, c = tj*64+tx*4+j;
      Mb[r*JD+c] = acc[i][j];
      if (ti != tj) Mb[c*JD+r] = acc[i][j];
    }
}

// ---------------------------------------------------------------------------
// K5: recon = A * M, fused depatchify. grid (128 patch-blocks, 16 batches).
// ---------------------------------------------------------------------------
__global__ __launch_bounds__(256) void k_recon(const float* __restrict__ x,
                                               const float* __restrict__ Mg,
                                               float* __restrict__ out) {
  const int nb = blockIdx.x;
  const int b  = blockIdx.y;
  const int t  = threadIdx.x;
  __shared__ float At[32][17];
  __shared__ float Mt[16][JD];
  const float* xb = x + (size_t)b*3*IMG*IMG;
  const float* Mb = Mg + (size_t)b*JD*JD;
  float* ob = out + (size_t)b*3*IMG*IMG;
  const int pg = t >> 4;
  const int jg = t & 15;
  float acc[2][12];
#pragma unroll
  for (int i=0;i<2;i++)
#pragma unroll
    for (int j=0;j<12;j++) acc[i][j]=0.f;
  for (int j0=0; j0<JD; j0+=16) {
    for (int f=t; f<512; f+=256) {
      const int nl = f >> 4, jj = f & 15;
      const int j = j0 + jj;
      const int n = nb*32 + nl;
      const int hh = n >> 6, ww = n & 63;
      const int c = j >> 6, p = (j >> 3) & 7, q = j & 7;
      At[nl][jj] = xb[(c*IMG + hh*8+p)*IMG + ww*8 + q];
    }
    for (int f=t; f<768; f+=256) {
      const int jj = f/48, cc = (f - jj*48)*4;
      *(float4*)(&Mt[jj][cc]) = *(const float4*)(Mb + (size_t)(j0+jj)*JD + cc);
    }
    __syncthreads();
#pragma unroll 4
    for (int jj=0;jj<16;jj++) {
      const float a0 = At[pg*2+0][jj];
      const float a1 = At[pg*2+1][jj];
      const float4 m0 = *(const float4*)(&Mt[jj][jg*12]);
      const float4 m1 = *(const float4*)(&Mt[jj][jg*12+4]);
      const float4 m2 = *(const float4*)(&Mt[jj][jg*12+8]);
      const float mm[12] = {m0.x,m0.y,m0.z,m0.w,m1.x,m1.y,m1.z,m1.w,
                            m2.x,m2.y,m2.z,m2.w};
#pragma unroll
      for (int j=0;j<12;j++) {
        acc[0][j] += a0*mm[j];
        acc[1][j] += a1*mm[j];
      }
    }
    __syncthreads();
  }
#pragma unroll
  for (int i=0;i<2;i++) {
    const int n = nb*32 + pg*2 + i;
    const int hh = n >> 6, ww = n & 63;
#pragma unroll
    for (int j4=0;j4<3;j4++) {
      const int jo = jg*12 + j4*4;
      const int c = jo >> 6, p = (jo >> 3) & 7, q = jo & 7;
      const float4 v = make_float4(acc[i][j4*4+0], acc[i][j4*4+1],
                                   acc[i][j4*4+2], acc[i][j4*4+3]);
      *(float4*)(ob + (size_t)(c*IMG + hh*8+p)*IMG + ww*8 + q) = v;
    }
  }
}

// ---------------------------------------------------------------------------
extern "C" void kernel_launch(void* const* d_in, const int* in_sizes, int n_in,
                              void* d_out, int out_size, void* d_ws, size_t ws_size,
                              hipStream_t stream) {
  (void)in_sizes; (void)n_in; (void)out_size; (void)ws_size;
  const float* x = (const float*)d_in[0];
  float* out = (float*)d_out;
  float* ws  = (float*)d_ws;

  float* part = ws;                    // dead after k_greduce
  float* Gs   = ws + 2359296;
  float* P0   = ws + 2949120;
  float* P1   = ws + 3538944;
  // overlays on the (dead) part region:
  float* Mg   = ws;                    // 589824
  float* Wb   = ws + 786432;           // 196608
  float* Hg   = ws + 983040;           // 66560 (64x65 per batch)
  float* Vtg  = ws + 1057792;          // 32768
  float* Btg  = ws + 1090560;          // 98304 (32x192 per batch)

  k_gram  <<<dim3(4,4,16), 512, 0, stream>>>(x, part);
  k_greduce<<<2304,        256, 0, stream>>>(part, Gs);
  k_sq    <<<dim3(6,16),   256, 0, stream>>>(Gs, P0);   // Gs^2
  k_sq    <<<dim3(6,16),   256, 0, stream>>>(P0, P1);   // Gs^4
  k_sq    <<<dim3(6,16),   256, 0, stream>>>(P1, P0);   // Gs^8
  k_sq    <<<dim3(6,16),   256, 0, stream>>>(P0, P1);   // Gs^16
  k_sq    <<<dim3(6,16),   256, 0, stream>>>(P1, P0);   // Gs^32
  k_subH  <<<16,           512, 0, stream>>>(P0, Gs, Wb, Hg);
  k_eigv  <<<16,           256, 0, stream>>>(Hg, Vtg);
  k_bv    <<<16,           256, 0, stream>>>(Wb, Vtg, Btg);
  k_mm    <<<dim3(6,16),   256, 0, stream>>>(Btg, Mg);
  k_recon <<<dim3(128,16), 256, 0, stream>>>(x, Mg, out);
}

// Round 11
// 854.318 us; speedup vs baseline: 1.1164x; 1.0092x over previous
//
#include <hip/hip_runtime.h>
#include <cstdint>
#include <cstddef>

#define IMG 512
#define JD 192

__device__ inline float fast_rcp(float x) { return __builtin_amdgcn_rcpf(x); }

// ---------------------------------------------------------------------------
// K1: partial Gram. grid (4 chunks, 4 slabs, 16 batches), 512 thr.
// Two 256-thread groups split the 32-patch nl range; 6x6 tiles; float2 LDS
// reads; float4 global staging; double-buffered tile with issue-early /
// write-late split (one barrier per 32-patch step).
// ---------------------------------------------------------------------------
__global__ __launch_bounds__(512) void k_gram(const float* __restrict__ x,
                                              float* __restrict__ part) {
  const int ck = blockIdx.x;
  const int sl = blockIdx.y;
  const int b  = blockIdx.z;
  const int t  = threadIdx.x;
  __shared__ float tile[2][32][JD];    // 49.2 KB
  __shared__ float pacc[256*37];       // 37.9 KB (group-1 partials)
  const int g   = t >> 8;              // 0 or 1
  const int tid = t & 255;
  const int ty = tid >> 5;
  const int tx = tid & 31;
  const int r0 = sl*48 + ty*6;
  const int c0 = tx*6;
  float acc[6][6];
#pragma unroll
  for (int i=0;i<6;i++)
#pragma unroll
    for (int j=0;j<6;j++) acc[i][j]=0.f;
  const float* xb = x + (size_t)b*3*IMG*IMG;
  const int nbeg = ck*1024;
  const int nlo = g*16, nhi = nlo+16;

  int snl[3]; size_t cpo[3]; float* wp0[3];
#pragma unroll
  for (int k=0;k<3;k++) {
    const int f = t + k*512;
    const int nl = f/48, j4 = f - nl*48;
    const int c = j4 >> 4, p = (j4 >> 1) & 7, q = (j4 & 1)*4;
    snl[k] = nl;
    cpo[k] = (size_t)(c*IMG + p)*IMG + q;
    wp0[k] = &tile[0][nl][j4*4];
  }
  float4 regs[3];
#pragma unroll
  for (int k=0;k<3;k++) {
    const int n = nbeg + snl[k];
    regs[k] = *(const float4*)(xb + cpo[k] + (size_t)(n>>6)*8*IMG + (n&63)*8);
  }
#pragma unroll
  for (int k=0;k<3;k++) *(float4*)wp0[k] = regs[k];
  __syncthreads();

  int cur = 0;
  for (int it=0; it<32; it++) {
    if (it < 31) {
      const int n0 = nbeg + (it+1)*32;
#pragma unroll
      for (int k=0;k<3;k++) {
        const int n = n0 + snl[k];
        regs[k] = *(const float4*)(xb + cpo[k] + (size_t)(n>>6)*8*IMG + (n&63)*8);
      }
    }
    const float* tb = &tile[cur][0][0];
#pragma unroll 4
    for (int nl = nlo; nl < nhi; nl++) {
      const float* tr = tb + nl*JD;
      const float2 a01 = *(const float2*)(tr + r0);
      const float2 a23 = *(const float2*)(tr + r0+2);
      const float2 a45 = *(const float2*)(tr + r0+4);
      const float2 b01 = *(const float2*)(tr + c0);
      const float2 b23 = *(const float2*)(tr + c0+2);
      const float2 b45 = *(const float2*)(tr + c0+4);
      const float va[6] = {a01.x,a01.y,a23.x,a23.y,a45.x,a45.y};
      const float vb[6] = {b01.x,b01.y,b23.x,b23.y,b45.x,b45.y};
#pragma unroll
      for (int i=0;i<6;i++)
#pragma unroll
        for (int j=0;j<6;j++) acc[i][j] += va[i]*vb[j];
    }
    if (it < 31) {
#pragma unroll
      for (int k=0;k<3;k++) *(float4*)(wp0[k] + (cur^1)*6144) = regs[k];
    }
    __syncthreads();
    cur ^= 1;
  }
  if (g == 1) {
#pragma unroll
    for (int i=0;i<6;i++)
#pragma unroll
      for (int j=0;j<6;j++) pacc[tid*37 + i*6+j] = acc[i][j];
  }
  __syncthreads();
  if (g == 0) {
    float* dst = part + (((size_t)(b*4 + sl))*4 + ck) * (size_t)(48*JD);
#pragma unroll
    for (int i=0;i<6;i++)
#pragma unroll
      for (int j=0;j<6;j++)
        dst[(ty*6+i)*JD + c0+j] = acc[i][j] + pacc[tid*37 + i*6+j];
  }
}

// ---------------------------------------------------------------------------
// K2: reduce 4 chunk-partials -> Gs = G / 4096
// ---------------------------------------------------------------------------
__global__ __launch_bounds__(256) void k_greduce(const float* __restrict__ part,
                                                 float* __restrict__ Gs) {
  const int idx = blockIdx.x*256 + threadIdx.x;
  const int b = idx / (JD*JD);
  const int e = idx - b*(JD*JD);
  const int r = e / JD;
  const int sl = r / 48;
  const int w = (r - sl*48)*JD + (e - r*JD);
  const float* p = part + ((size_t)(b*4+sl))*4*(48*JD) + w;
  float s = 0.f;
#pragma unroll
  for (int ck=0; ck<4; ck++) s += p[(size_t)ck*48*JD];
  Gs[idx] = s * (1.0f/4096.0f);
}

// ---------------------------------------------------------------------------
// K3: D = S*S for symmetric S (per batch), lower-tri tile pairs. 256 thr.
// ---------------------------------------------------------------------------
__global__ __launch_bounds__(256) void k_sq(const float* __restrict__ S,
                                            float* __restrict__ D) {
  const int tp = blockIdx.x;
  const int b  = blockIdx.y;
  int ti, tj;
  if      (tp==0){ti=0;tj=0;} else if (tp==1){ti=1;tj=0;}
  else if (tp==2){ti=1;tj=1;} else if (tp==3){ti=2;tj=0;}
  else if (tp==4){ti=2;tj=1;} else            {ti=2;tj=2;}
  const float* Sb = S + (size_t)b*JD*JD;
  float* Db = D + (size_t)b*JD*JD;
  __shared__ float Ar[64][33];
  __shared__ float Br[64][33];
  const int t = threadIdx.x;
  const int ty = t >> 4, tx = t & 15;
  float acc[4][4];
#pragma unroll
  for (int i=0;i<4;i++)
#pragma unroll
    for (int j=0;j<4;j++) acc[i][j]=0.f;
  for (int k0=0; k0<JD; k0+=32) {
    for (int f=t; f<2048; f+=256) {
      const int row = f >> 5, kk = f & 31;
      Ar[row][kk] = Sb[(ti*64+row)*JD + k0+kk];
      Br[row][kk] = Sb[(tj*64+row)*JD + k0+kk];
    }
    __syncthreads();
#pragma unroll 4
    for (int k=0;k<32;k++) {
      float va[4], vb[4];
#pragma unroll
      for (int i=0;i<4;i++) va[i] = Ar[ty*4+i][k];
#pragma unroll
      for (int j=0;j<4;j++) vb[j] = Br[tx*4+j][k];
#pragma unroll
      for (int i=0;i<4;i++)
#pragma unroll
        for (int j=0;j<4;j++) acc[i][j] += va[i]*vb[j];
    }
    __syncthreads();
  }
#pragma unroll
  for (int i=0;i<4;i++)
#pragma unroll
    for (int j=0;j<4;j++) {
      const int r = ti*64+ty*4+i, c = tj*64+tx*4+j;
      Db[r*JD+c] = acc[i][j];
      if (ti != tj) Db[c*JD+r] = acc[i][j];
    }
}

// ---------------------------------------------------------------------------
// LDS-resident helpers for k_subH (512 threads). W: 192 rows, stride 68.
// ---------------------------------------------------------------------------

// In-place ridge-CholQR of Wl (192x68 LDS). S1 is 64x68 LDS scratch.
// Wpart = partner W buffer (dead), used for split-K Gram partials. BD=512.
__device__ void orth_lds(float* __restrict__ Wl, float* __restrict__ Wpart,
                         float* __restrict__ S1,
                         float* __restrict__ rdv, float* __restrict__ pdv,
                         float* __restrict__ misc, int t, float ridge) {
  const int g = t >> 8;                 // split-K group 0/1
  const int tid = t & 255;
  const int ty = tid >> 4, tx = tid & 15;   // 16x16 grid -> 4x4 outputs
  float acc[4][4];
#pragma unroll
  for (int i=0;i<4;i++)
#pragma unroll
    for (int j=0;j<4;j++) acc[i][j]=0.f;
  __syncthreads();
  // ---- Gram: S1 = W^T W, split-K (group g sums rows [96g, 96g+96)) ----
  {
    const int rbeg = g*96;
#pragma unroll 2
    for (int r=rbeg; r<rbeg+96; r++) {
      const float4 va4 = *(const float4*)(Wl + r*68 + ty*4);
      const float4 vb4 = *(const float4*)(Wl + r*68 + tx*4);
      const float a4[4] = {va4.x, va4.y, va4.z, va4.w};
      const float b4[4] = {vb4.x, vb4.y, vb4.z, vb4.w};
#pragma unroll
      for (int i=0;i<4;i++)
#pragma unroll
        for (int j=0;j<4;j++) acc[i][j] += a4[i]*b4[j];
    }
  }
  if (g == 1) {
#pragma unroll
    for (int i=0;i<4;i++)
#pragma unroll
      for (int j=0;j<4;j++)
        Wpart[(ty*4+i)*68 + tx*4+j] = acc[i][j];
  }
  __syncthreads();
  if (g == 0) {
#pragma unroll
    for (int i=0;i<4;i++)
#pragma unroll
      for (int j=0;j<4;j++)
        S1[(ty*4+i)*68 + tx*4+j] = acc[i][j] + Wpart[(ty*4+i)*68 + tx*4+j];
  }
  __syncthreads();
  // ---- ridge ----
  if (ridge > 0.f) {
    if (t < 64) {
      float d = S1[t*68+t];
#pragma unroll
      for (int o=1;o<64;o<<=1) d = fmaxf(d, __shfl_xor(d, o));
      if (t == 0) misc[0] = d * ridge;
    }
    __syncthreads();
    if (t < 64) S1[t*68+t] += misc[0];
    __syncthreads();
  }
  // ---- blocked Cholesky (LDL-form, panel = 16) ----
  for (int p=0; p<4; p++) {
    const int b16 = p*16;
    // phase A: diagonal 16x16 factor, single wave, no barriers
    if (t < 64) {
      for (int jj=0; jj<16; jj++) {
        const int j = b16 + jj;
        const float invd = fast_rcp(S1[j*68+j]);
        if (t == 0) pdv[jj] = invd;
        const int nit = (15-jj)*16;
        for (int f=t; f<nit; f+=64) {
          const int i = j+1 + (f>>4);
          const int k = j+1 + (f&15);
          if (k <= i)
            S1[i*68+k] -= S1[i*68+j]*S1[k*68+j]*invd;
        }
      }
    }
    __syncthreads();
    // phase B: panel rows below diag block, one thread per row (registers)
    const int rb = b16 + 16;
    if (t < 64 - rb) {
      const int r = rb + t;
      float pr[16];
      float4* prp = (float4*)pr;
      prp[0] = *(const float4*)(S1 + r*68 + b16);
      prp[1] = *(const float4*)(S1 + r*68 + b16 + 4);
      prp[2] = *(const float4*)(S1 + r*68 + b16 + 8);
      prp[3] = *(const float4*)(S1 + r*68 + b16 + 12);
#pragma unroll
      for (int c=1; c<16; c++) {
        float s = pr[c];
#pragma unroll
        for (int j=0; j<c; j++) s -= pr[j]*S1[(b16+c)*68 + b16+j]*pdv[j];
        pr[c] = s;
      }
      *(float4*)(S1 + r*68 + b16)      = prp[0];
      *(float4*)(S1 + r*68 + b16 + 4)  = prp[1];
      *(float4*)(S1 + r*68 + b16 + 8)  = prp[2];
      *(float4*)(S1 + r*68 + b16 + 12) = prp[3];
    }
    __syncthreads();
    // phase C: trailing rank-16 update, fully parallel (stride 512)
    for (int f=t; f<2304; f+=512) {
      const int i = rb + f/48;
      const int k = rb + (f - (f/48)*48);
      if (i < 64 && k < 64 && k <= i) {
        float s = S1[i*68+k];
#pragma unroll
        for (int jj=0; jj<16; jj++)
          s -= S1[i*68 + b16+jj]*S1[k*68 + b16+jj]*pdv[jj];
        S1[i*68+k] = s;
      }
    }
    __syncthreads();
  }
  // ---- scale columns, triangular solve in registers ----
  if (t < 64) rdv[t] = rsqrtf(S1[t*68+t]);
  __syncthreads();
  for (int f=t; f<4096; f+=512) {
    const int i = f>>6, k = f&63;
    if (k < i) S1[i*68+k] *= rdv[k];
  }
  __syncthreads();
  if (t < JD) {
    float w[64];
    float4* wp = (float4*)w;
#pragma unroll
    for (int c4=0;c4<16;c4++) wp[c4] = *(const float4*)(Wl + t*68 + c4*4);
#pragma unroll
    for (int c=0;c<64;c++) {
      float v = w[c];
#pragma unroll
      for (int k=0;k<c;k++) v -= w[k]*S1[c*68+k];
      w[c] = v * rdv[c];
    }
#pragma unroll
    for (int c4=0;c4<16;c4++) *(float4*)(Wl + t*68 + c4*4) = wp[c4];
  }
  __syncthreads();
}

// Wout(192x68 LDS) = G(192x192 global) * Win(192x68 LDS); Gt 32x196 scratch.
// 384 active compute threads: 4-row x 8-col tiles, all-b128 LDS reads. BD=512.
__device__ void mm_lds(const float* __restrict__ G, const float* __restrict__ Win,
                       float* __restrict__ Wout, float* __restrict__ Gt, int t) {
  const int rg = t >> 3;   // 0..47 -> rows rg*4..+3 (t<384)
  const int cg = t & 7;    // cols cg*8..+7
  float acc[4][8];
#pragma unroll
  for (int i=0;i<4;i++)
#pragma unroll
    for (int j=0;j<8;j++) acc[i][j]=0.f;
  for (int k0=0; k0<JD; k0+=32) {
    __syncthreads();
    // stage Gt[kk][r] at stride 196 (consecutive lanes -> consecutive r)
    for (int f=t; f<6144; f+=512) {
      const int kk = f / 192, r = f - kk*192;
      Gt[kk*196 + r] = G[r*JD + k0 + kk];
    }
    __syncthreads();
    if (t < 384) {
#pragma unroll 2
      for (int k=0;k<32;k++) {
        const float4 g4 = *(const float4*)(Gt + k*196 + rg*4);
        const float* wr = Win + (k0+k)*68 + cg*8;
        const float4 w0 = *(const float4*)(wr);
        const float4 w1 = *(const float4*)(wr + 4);
        const float ga[4] = {g4.x, g4.y, g4.z, g4.w};
        const float wb[8] = {w0.x,w0.y,w0.z,w0.w,w1.x,w1.y,w1.z,w1.w};
#pragma unroll
        for (int i=0;i<4;i++)
#pragma unroll
          for (int j=0;j<8;j++) acc[i][j] += ga[i]*wb[j];
      }
    }
  }
  __syncthreads();
  if (t < 384) {
#pragma unroll
    for (int i=0;i<4;i++)
#pragma unroll
      for (int j=0;j<8;j++)
        Wout[(rg*4+i)*68 + cg*8 + j] = acc[i][j];
  }
  __syncthreads();
}

// S1 = X^T * Y (both 192x68 LDS), dst stride ss. BD=512.
__device__ void hgemm_lds(const float* __restrict__ X, const float* __restrict__ Y,
                          float* __restrict__ S1, int ss, int t) {
  const int ty = t >> 5, tx = t & 31;
  float acc[4][2];
#pragma unroll
  for (int i=0;i<4;i++)
#pragma unroll
    for (int j=0;j<2;j++) acc[i][j]=0.f;
#pragma unroll 2
  for (int r=0; r<JD; r++) {
    const float4 va4 = *(const float4*)(X + r*68 + ty*4);
    const float2 vb2 = *(const float2*)(Y + r*68 + tx*2);
    const float a4[4] = {va4.x, va4.y, va4.z, va4.w};
    const float b2[2] = {vb2.x, vb2.y};
#pragma unroll
    for (int i=0;i<4;i++)
#pragma unroll
      for (int j=0;j<2;j++) acc[i][j] += a4[i]*b2[j];
  }
  __syncthreads();
#pragma unroll
  for (int i=0;i<4;i++)
#pragma unroll
    for (int j=0;j<2;j++)
      S1[(ty*4+i)*ss + tx*2+j] = acc[i][j];
  __syncthreads();
}

// ---------------------------------------------------------------------------
// K4a: subspace basis + H, all W traffic in LDS. grid 16, 512 thr.
// ---------------------------------------------------------------------------
__global__ __launch_bounds__(512) void k_subH(const float* __restrict__ G32g,
                                              const float* __restrict__ Gsg,
                                              float* __restrict__ WbG,
                                              float* __restrict__ Hgg) {
  const int b = blockIdx.x;
  const int t = threadIdx.x;
  __shared__ __align__(16) float W0l[192*68];
  __shared__ __align__(16) float W1l[192*68];
  __shared__ __align__(16) float scr[32*196]; // S1(64x68)/Gt(32x196)/H(64x65)
  __shared__ float rdv[64];
  __shared__ float pdv[16];
  __shared__ float misc[8];
  const float* Gb  = G32g + (size_t)b*JD*JD;
  const float* Gsb = Gsg  + (size_t)b*JD*JD;

  for (int f=t; f<JD*64; f+=512)
    W0l[(f>>6)*68 + (f&63)] = Gb[(f>>6)*JD + (f&63)];
  __syncthreads();

  orth_lds(W0l, W1l, scr, rdv, pdv, misc, t, 1e-6f); // W1l dead: partials ok
  mm_lds(Gb, W0l, W1l, scr, t);                      // power +32
  orth_lds(W1l, W0l, scr, rdv, pdv, misc, t, 1e-6f); // W0l dead now
  orth_lds(W1l, W0l, scr, rdv, pdv, misc, t, 0.f);   // CholQR2 clean pass

  // H = W^T Gs W  (T1 = Gs*W into W0l, then hgemm -> scr at stride 65)
  mm_lds(Gsb, W1l, W0l, scr, t);
  hgemm_lds(W1l, W0l, scr, 65, t);

  float* Wb = WbG + (size_t)b*JD*64;
  for (int f=t; f<JD*64; f+=512)
    Wb[f] = W1l[(f>>6)*68 + (f&63)];
  float* Hb = Hgg + (size_t)b*4160;
  for (int f=t; f<4160; f+=512) Hb[f] = scr[f];
}

// ---------------------------------------------------------------------------
// Householder tridiag of A (64x64, stride 65) in place (256-thread update).
// ---------------------------------------------------------------------------
__device__ void dev_tridiag(float* __restrict__ A, float* a, float* b2,
                            float* bsg, float* v0s, float* bts,
                            float* vvec, float* wvec, int t) {
  for (int j=0; j<=61; j++) {
    const int m = 63 - j;
    if (t < 64) {
      float xi = (t < m) ? A[j*65 + (j+1+t)] : 0.f;
      float nr = xi*xi;
#pragma unroll
      for (int o=1;o<64;o<<=1) nr += __shfl_xor(nr, o);
      const float sig = sqrtf(nr);
      const float alpha = __shfl(xi, 0);
      const float sgn = (alpha >= 0.f) ? 1.f : -1.f;
      const float v0 = alpha + sgn*sig;
      const float beta = (sig > 1e-20f) ? 1.0f/(sig*fabsf(v0)) : 0.f;
      if (t < m) vvec[t] = (t==0) ? v0 : xi;
      if (t == 0) {
        a[j] = A[j*65+j]; b2[j] = nr; bsg[j] = -sgn*sig;
        v0s[j] = v0; bts[j] = beta;
      }
      float pv = 0.f;
      if (t < m) {
        const float* row = A + (j+1+t)*65 + (j+1);
        for (int c=0;c<m;c++) pv += row[c]*vvec[c];
        pv *= beta;
      }
      float dp = (t<m) ? vvec[t]*pv : 0.f;
#pragma unroll
      for (int o=1;o<64;o<<=1) dp += __shfl_xor(dp, o);
      const float gamma = 0.5f*beta*dp;
      if (t < m) wvec[t] = pv - gamma*vvec[t];
    }
    __syncthreads();
    const int mm = m*m;
    for (int f=t; f<mm; f+=256) {
      const int r = f/m, c = f - r*m;
      A[(j+1+r)*65 + (j+1+c)] -= vvec[r]*wvec[c] + wvec[r]*vvec[c];
    }
    __syncthreads();
  }
  if (t == 0) {
    a[62] = A[62*65+62];
    a[63] = A[63*65+63];
    const float bb = A[62*65+63];
    b2[62] = bb*bb;
    bsg[62] = bb;
  }
  __syncthreads();
}

// Sturm count with fast reciprocal
__device__ inline int sturm_cnt_fast(const float* a, const float* b2, float sig) {
  float d = a[0] - sig;
  int n = (d < 0.f) ? 1 : 0;
#pragma unroll 8
  for (int i=1;i<64;i++) {
    const float dd = (fabsf(d) < 1e-20f) ? -1e-20f : d;
    d = (a[i]-sig) - b2[i-1]*fast_rcp(dd);
    n += (d < 0.f) ? 1 : 0;
  }
  return n;
}

__device__ inline float dguard(float d) {
  if (fabsf(d) < 1e-12f) return (d < 0.f) ? -1e-12f : 1e-12f;
  return d;
}

// ---------------------------------------------------------------------------
// K4b: tridiag + eigenvalues + twisted + CholQR32 + backtransform, fused
// (SH stays in LDS between tridiag and backtransform). grid 16, 256 thr.
// ---------------------------------------------------------------------------
__global__ __launch_bounds__(256) void k_eigv(const float* __restrict__ Hgg,
                                              float* __restrict__ VtG) {
  const int b = blockIdx.x;
  const int t = threadIdx.x;
  __shared__ float SH[4160];
  __shared__ float Vt[64*36];
  __shared__ float dpA[64*33];
  __shared__ float dmA[64*33];
  __shared__ float ps[8*33];
  __shared__ float wvred[32];
  __shared__ float rdv[64];
  __shared__ float a64[64];
  __shared__ float b2v[64];
  __shared__ float bsg[64];
  __shared__ float v0s[64];
  __shared__ float bts[64];
  __shared__ float vvec[64];
  __shared__ float wvec[64];
  __shared__ float lam[32];
  __shared__ float misc[8];
  const float* Hb = Hgg + (size_t)b*4160;
  for (int f=t; f<4160; f+=256) SH[f] = Hb[f];
  __syncthreads();

  dev_tridiag(SH, a64, b2v, bsg, v0s, bts, vvec, wvec, t);

  // ---- spectrum bounds (Gershgorin) ----
  if (t < 64) {
    const float bl = (t>0)  ? sqrtf(b2v[t-1]) : 0.f;
    const float br = (t<63) ? sqrtf(b2v[t])   : 0.f;
    float lo = a64[t] - bl - br, hi = a64[t] + bl + br;
#pragma unroll
    for (int o=1;o<64;o<<=1) {
      lo = fminf(lo, __shfl_xor(lo,o));
      hi = fmaxf(hi, __shfl_xor(hi,o));
    }
    if (t == 0) { misc[0] = lo - 1e-4f; misc[1] = hi + 1e-4f; }
  }
  __syncthreads();

  // ---- 9-section search: 8 probes/eig in parallel, 10 rounds ----
  {
    const int l = t >> 3, g = t & 7;
    const int r = 32 + l;
    float L = misc[0], H = misc[1];
    for (int it=0; it<10; it++) {
      const float mid = L + (H-L)*((float)(g+1)*(1.0f/9.0f));
      const int cnt = sturm_cnt_fast(a64, b2v, mid);
      float nL = L, nH = H;
#pragma unroll
      for (int k=0;k<8;k++) {
        const int ck = __shfl(cnt, k, 8);
        const float pk = L + (H-L)*((float)(k+1)*(1.0f/9.0f));
        if (ck <= r) nL = fmaxf(nL, pk); else nH = fminf(nH, pk);
      }
      L = nL; H = nH;
    }
    if (g == 0) lam[l] = 0.5f*(L+H);
  }
  __syncthreads();

  // ---- twisted-factorization inverse iteration (lane l = one eigvec) ----
  if (t < 32) {
    const int l = t;
    const float lm = lam[l];
    float d = dguard(a64[0] - lm);
    dpA[0*33+l] = d;
    for (int i=1;i<64;i++) {
      d = dguard((a64[i]-lm) - b2v[i-1]*fast_rcp(d));
      dpA[i*33+l] = d;
    }
    float e = dguard(a64[63] - lm);
    dmA[63*33+l] = e;
    for (int i=62;i>=0;i--) {
      e = dguard((a64[i]-lm) - b2v[i]*fast_rcp(e));
      dmA[i*33+l] = e;
    }
    int ks = 0; float gbest = 1e30f;
    for (int i=0;i<64;i++) {
      const float g = fabsf(dpA[i*33+l] + dmA[i*33+l] - (a64[i]-lm));
      if (g < gbest) { gbest = g; ks = i; }
    }
    Vt[ks*36+l] = 1.f;
    float z = 1.f;
    for (int i=ks-1;i>=0;i--) {
      z = -(bsg[i]*z) * fast_rcp(dpA[i*33+l]);
      z = fminf(fmaxf(z, -1e18f), 1e18f);
      Vt[i*36+l] = z;
    }
    z = 1.f;
    for (int i=ks+1;i<64;i++) {
      z = -(bsg[i-1]*z) * fast_rcp(dmA[i*33+l]);
      z = fminf(fmaxf(z, -1e18f), 1e18f);
      Vt[i*36+l] = z;
    }
    float nr2 = 0.f;
    for (int i=0;i<64;i++) { const float zz = Vt[i*36+l]; nr2 += zz*zz; }
    const float inv = rsqrtf(nr2);
    for (int i=0;i<64;i++) Vt[i*36+l] *= inv;
  }
  __syncthreads();

  // ---- CholQR-32 safety pass on Vt ----
  for (int f=t; f<1024; f+=256) {
    const int i = f>>5, j = f&31;
    float s = 0.f;
    for (int r=0;r<64;r++) s += Vt[r*36+i]*Vt[r*36+j];
    dpA[i*33+j] = s;
  }
  __syncthreads();
  if (t == 0) {
    float m = 0.f;
    for (int j=0;j<32;j++) m = fmaxf(m, dpA[j*33+j]);
    misc[2] = m * 1e-7f;
  }
  __syncthreads();
  if (t < 32) dpA[t*33+t] += misc[2];
  for (int j=0;j<31;j++) {
    __syncthreads();
    const float invd = fast_rcp(dpA[j*33+j]);
    for (int f=t; f<(31-j)*32; f+=256) {
      const int i = j+1 + (f>>5);
      const int k = f & 31;
      if (k > j && k <= i)
        dpA[i*33+k] -= dpA[i*33+j]*dpA[k*33+j]*invd;
    }
  }
  __syncthreads();
  if (t < 32) rdv[t] = rsqrtf(dpA[t*33+t]);
  __syncthreads();
  for (int f=t; f<1024; f+=256) {
    const int i = f>>5, k = f&31;
    if (k < i) dpA[i*33+k] *= rdv[k];
  }
  __syncthreads();
  if (t < 64) {
    float w[32];
#pragma unroll
    for (int c=0;c<32;c++) w[c] = Vt[t*36+c];
#pragma unroll
    for (int c=0;c<32;c++) {
      float v = w[c];
#pragma unroll
      for (int k=0;k<c;k++) v -= w[k]*dpA[c*33+k];
      w[c] = v * rdv[c];
    }
#pragma unroll
    for (int c=0;c<32;c++) Vt[t*36+c] = w[c];
  }
  __syncthreads();

  // ---- backtransform: V = H_0 H_1 ... H_61 Vt ----
  for (int j=61; j>=0; j--) {
    const int m = 63 - j;
    {
      const int c = t & 31, g = t >> 5;
      float s = 0.f;
      for (int r=g; r<m; r+=8) {
        const float vr = (r==0) ? v0s[j] : SH[j*65 + (j+1+r)];
        s += vr * Vt[(j+1+r)*36 + c];
      }
      ps[g*33+c] = s;
    }
    __syncthreads();
    if (t < 32) {
      float s = 0.f;
#pragma unroll
      for (int g=0;g<8;g++) s += ps[g*33+t];
      wvred[t] = s * bts[j];
    }
    __syncthreads();
    {
      const int c = t & 31, g = t >> 5;
      for (int r=g; r<m; r+=8) {
        const float vr = (r==0) ? v0s[j] : SH[j*65 + (j+1+r)];
        Vt[(j+1+r)*36 + c] -= vr * wvred[c];
      }
    }
    __syncthreads();
  }

  float* Vb = VtG + (size_t)b*2048;
  for (int f=t; f<2048; f+=256) Vb[f] = Vt[(f>>5)*36 + (f&31)];
}

// ---------------------------------------------------------------------------
// K4c: B^T = (W*V)^T -> Btg (32 x 192 row-major per batch). grid 16.
// ---------------------------------------------------------------------------
__global__ __launch_bounds__(256) void k_bv(const float* __restrict__ WbG,
                                            const float* __restrict__ VtG,
                                            float* __restrict__ Btg) {
  const int b = blockIdx.x;
  const int t = threadIdx.x;
  __shared__ float Vt[64*36];
  const float* W = WbG + (size_t)b*JD*64;
  const float* Vb = VtG + (size_t)b*2048;
  float* Bt = Btg + (size_t)b*32*JD;
  for (int f=t; f<2048; f+=256) Vt[(f>>5)*36 + (f&31)] = Vb[f];
  __syncthreads();
  if (t < JD) {
    float accv[32];
#pragma unroll
    for (int c=0;c<32;c++) accv[c] = 0.f;
    const float4* crow = (const float4*)(W + t*64);
#pragma unroll 2
    for (int kb=0; kb<16; kb++) {
      const float4 av = crow[kb];
      const float a4[4] = {av.x, av.y, av.z, av.w};
#pragma unroll
      for (int ki=0; ki<4; ki++) {
        const float aa = a4[ki];
        const float* vrow = Vt + (kb*4+ki)*36;
        const float4 v0 = *(const float4*)(vrow+0);
        const float4 v1 = *(const float4*)(vrow+4);
        const float4 v2 = *(const float4*)(vrow+8);
        const float4 v3 = *(const float4*)(vrow+12);
        const float4 v4 = *(const float4*)(vrow+16);
        const float4 v5 = *(const float4*)(vrow+20);
        const float4 v6 = *(const float4*)(vrow+24);
        const float4 v7 = *(const float4*)(vrow+28);
        accv[0]+=aa*v0.x; accv[1]+=aa*v0.y; accv[2]+=aa*v0.z; accv[3]+=aa*v0.w;
        accv[4]+=aa*v1.x; accv[5]+=aa*v1.y; accv[6]+=aa*v1.z; accv[7]+=aa*v1.w;
        accv[8]+=aa*v2.x; accv[9]+=aa*v2.y; accv[10]+=aa*v2.z; accv[11]+=aa*v2.w;
        accv[12]+=aa*v3.x; accv[13]+=aa*v3.y; accv[14]+=aa*v3.z; accv[15]+=aa*v3.w;
        accv[16]+=aa*v4.x; accv[17]+=aa*v4.y; accv[18]+=aa*v4.z; accv[19]+=aa*v4.w;
        accv[20]+=aa*v5.x; accv[21]+=aa*v5.y; accv[22]+=aa*v5.z; accv[23]+=aa*v5.w;
        accv[24]+=aa*v6.x; accv[25]+=aa*v6.y; accv[26]+=aa*v6.z; accv[27]+=aa*v6.w;
        accv[28]+=aa*v7.x; accv[29]+=aa*v7.y; accv[30]+=aa*v7.z; accv[31]+=aa*v7.w;
      }
    }
#pragma unroll
    for (int c=0;c<32;c++) Bt[c*JD + t] = accv[c];
  }
}

// ---------------------------------------------------------------------------
// K4d: M = B B^T = Bt^T Bt, lower-tri tile pairs. grid (6,16).
// ---------------------------------------------------------------------------
__global__ __launch_bounds__(256) void k_mm(const float* __restrict__ Btg,
                                            float* __restrict__ Mg) {
  const int tp = blockIdx.x;
  const int b  = blockIdx.y;
  int ti, tj;
  if      (tp==0){ti=0;tj=0;} else if (tp==1){ti=1;tj=0;}
  else if (tp==2){ti=1;tj=1;} else if (tp==3){ti=2;tj=0;}
  else if (tp==4){ti=2;tj=1;} else            {ti=2;tj=2;}
  const float* Bt = Btg + (size_t)b*32*JD;
  float* Mb = Mg + (size_t)b*JD*JD;
  __shared__ float Ar[32][68];
  __shared__ float Br[32][68];
  const int t = threadIdx.x;
  const int ty = t >> 4, tx = t & 15;
  for (int f=t; f<2048; f+=256) {
    const int k = f >> 6, c = f & 63;
    Ar[k][c] = Bt[k*JD + ti*64 + c];
    Br[k][c] = Bt[k*JD + tj*64 + c];
  }
  __syncthreads();
  float acc[4][4];
#pragma unroll
  for (int i=0;i<4;i++)
#pragma unroll
    for (int j=0;j<4;j++) acc[i][j]=0.f;
#pragma unroll 4
  for (int k=0;k<32;k++) {
    const float4 va4 = *(const float4*)(&Ar[k][ty*4]);
    const float4 vb4 = *(const float4*)(&Br[k][tx*4]);
    const float a4[4] = {va4.x, va4.y, va4.z, va4.w};
    const float b4[4] = {vb4.x, vb4.y, vb4.z, vb4.w};
#pragma unroll
    for (int i=0;i<4;i++)
#pragma unroll
      for (int j=0;j<4;j++) acc[i][j] += a4[i]*b4[j];
  }
#pragma unroll
  for (int i=0;i<4;i++)
#pragma unroll
    for (int j=0;j<4;j++) {
      const int r = ti*64+ty*4+i, c = tj*64+tx*4+j;
      Mb[r*JD+c] = acc[i][j];
      if (ti != tj) Mb[c*JD+r] = acc[i][j];
    }
}

// ---------------------------------------------------------------------------
// K5: recon = A * M, fused depatchify. grid (128 patch-blocks, 16 batches).
// ---------------------------------------------------------------------------
__global__ __launch_bounds__(256) void k_recon(const float* __restrict__ x,
                                               const float* __restrict__ Mg,
                                               float* __restrict__ out) {
  const int nb = blockIdx.x;
  const int b  = blockIdx.y;
  const int t  = threadIdx.x;
  __shared__ float At[32][17];
  __shared__ float Mt[16][JD];
  const float* xb = x + (size_t)b*3*IMG*IMG;
  const float* Mb = Mg + (size_t)b*JD*JD;
  float* ob = out + (size_t)b*3*IMG*IMG;
  const int pg = t >> 4;
  const int jg = t & 15;
  float acc[2][12];
#pragma unroll
  for (int i=0;i<2;i++)
#pragma unroll
    for (int j=0;j<12;j++) acc[i][j]=0.f;
  for (int j0=0; j0<JD; j0+=16) {
    for (int f=t; f<512; f+=256) {
      const int nl = f >> 4, jj = f & 15;
      const int j = j0 + jj;
      const int n = nb*32 + nl;
      const int hh = n >> 6, ww = n & 63;
      const int c = j >> 6, p = (j >> 3) & 7, q = j & 7;
      At[nl][jj] = xb[(c*IMG + hh*8+p)*IMG + ww*8 + q];
    }
    for (int f=t; f<768; f+=256) {
      const int jj = f/48, cc = (f - jj*48)*4;
      *(float4*)(&Mt[jj][cc]) = *(const float4*)(Mb + (size_t)(j0+jj)*JD + cc);
    }
    __syncthreads();
#pragma unroll 4
    for (int jj=0;jj<16;jj++) {
      const float a0 = At[pg*2+0][jj];
      const float a1 = At[pg*2+1][jj];
      const float4 m0 = *(const float4*)(&Mt[jj][jg*12]);
      const float4 m1 = *(const float4*)(&Mt[jj][jg*12+4]);
      const float4 m2 = *(const float4*)(&Mt[jj][jg*12+8]);
      const float mm[12] = {m0.x,m0.y,m0.z,m0.w,m1.x,m1.y,m1.z,m1.w,
                            m2.x,m2.y,m2.z,m2.w};
#pragma unroll
      for (int j=0;j<12;j++) {
        acc[0][j] += a0*mm[j];
        acc[1][j] += a1*mm[j];
      }
    }
    __syncthreads();
  }
#pragma unroll
  for (int i=0;i<2;i++) {
    const int n = nb*32 + pg*2 + i;
    const int hh = n >> 6, ww = n & 63;
#pragma unroll
    for (int j4=0;j4<3;j4++) {
      const int jo = jg*12 + j4*4;
      const int c = jo >> 6, p = (jo >> 3) & 7, q = jo & 7;
      const float4 v = make_float4(acc[i][j4*4+0], acc[i][j4*4+1],
                                   acc[i][j4*4+2], acc[i][j4*4+3]);
      *(float4*)(ob + (size_t)(c*IMG + hh*8+p)*IMG + ww*8 + q) = v;
    }
  }
}

// ---------------------------------------------------------------------------
extern "C" void kernel_launch(void* const* d_in, const int* in_sizes, int n_in,
                              void* d_out, int out_size, void* d_ws, size_t ws_size,
                              hipStream_t stream) {
  (void)in_sizes; (void)n_in; (void)out_size; (void)ws_size;
  const float* x = (const float*)d_in[0];
  float* out = (float*)d_out;
  float* ws  = (float*)d_ws;

  float* part = ws;                    // dead after k_greduce
  float* Gs   = ws + 2359296;
  float* P0   = ws + 2949120;
  float* P1   = ws + 3538944;
  // overlays on the (dead) part region:
  float* Mg   = ws;                    // 589824
  float* Wb   = ws + 786432;           // 196608
  float* Hg   = ws + 983040;           // 66560 (64x65 per batch)
  float* Vtg  = ws + 1057792;          // 32768
  float* Btg  = ws + 1090560;          // 98304 (32x192 per batch)

  k_gram  <<<dim3(4,4,16), 512, 0, stream>>>(x, part);
  k_greduce<<<2304,        256, 0, stream>>>(part, Gs);
  k_sq    <<<dim3(6,16),   256, 0, stream>>>(Gs, P0);   // Gs^2
  k_sq    <<<dim3(6,16),   256, 0, stream>>>(P0, P1);   // Gs^4
  k_sq    <<<dim3(6,16),   256, 0, stream>>>(P1, P0);   // Gs^8
  k_sq    <<<dim3(6,16),   256, 0, stream>>>(P0, P1);   // Gs^16
  k_sq    <<<dim3(6,16),   256, 0, stream>>>(P1, P0);   // Gs^32
  k_subH  <<<16,           512, 0, stream>>>(P0, Gs, Wb, Hg);
  k_eigv  <<<16,           256, 0, stream>>>(Hg, Vtg);
  k_bv    <<<16,           256, 0, stream>>>(Wb, Vtg, Btg);
  k_mm    <<<dim3(6,16),   256, 0, stream>>>(Btg, Mg);
  k_recon <<<dim3(128,16), 256, 0, stream>>>(x, Mg, out);
}

// Round 12
// 782.915 us; speedup vs baseline: 1.2183x; 1.0912x over previous
//
#include <hip/hip_runtime.h>
#include <cstdint>
#include <cstddef>

#define IMG 512
#define JD 192

__device__ inline float fast_rcp(float x) { return __builtin_amdgcn_rcpf(x); }

// ---------------------------------------------------------------------------
// K1: partial Gram. grid (4 chunks, 4 slabs, 16 batches), 512 thr.
// ---------------------------------------------------------------------------
__global__ __launch_bounds__(512) void k_gram(const float* __restrict__ x,
                                              float* __restrict__ part) {
  const int ck = blockIdx.x;
  const int sl = blockIdx.y;
  const int b  = blockIdx.z;
  const int t  = threadIdx.x;
  __shared__ float tile[2][32][JD];    // 49.2 KB
  __shared__ float pacc[256*37];       // 37.9 KB (group-1 partials)
  const int g   = t >> 8;              // 0 or 1
  const int tid = t & 255;
  const int ty = tid >> 5;
  const int tx = tid & 31;
  const int r0 = sl*48 + ty*6;
  const int c0 = tx*6;
  float acc[6][6];
#pragma unroll
  for (int i=0;i<6;i++)
#pragma unroll
    for (int j=0;j<6;j++) acc[i][j]=0.f;
  const float* xb = x + (size_t)b*3*IMG*IMG;
  const int nbeg = ck*1024;
  const int nlo = g*16, nhi = nlo+16;

  int snl[3]; size_t cpo[3]; float* wp0[3];
#pragma unroll
  for (int k=0;k<3;k++) {
    const int f = t + k*512;
    const int nl = f/48, j4 = f - nl*48;
    const int c = j4 >> 4, p = (j4 >> 1) & 7, q = (j4 & 1)*4;
    snl[k] = nl;
    cpo[k] = (size_t)(c*IMG + p)*IMG + q;
    wp0[k] = &tile[0][nl][j4*4];
  }
  float4 regs[3];
#pragma unroll
  for (int k=0;k<3;k++) {
    const int n = nbeg + snl[k];
    regs[k] = *(const float4*)(xb + cpo[k] + (size_t)(n>>6)*8*IMG + (n&63)*8);
  }
#pragma unroll
  for (int k=0;k<3;k++) *(float4*)wp0[k] = regs[k];
  __syncthreads();

  int cur = 0;
  for (int it=0; it<32; it++) {
    if (it < 31) {
      const int n0 = nbeg + (it+1)*32;
#pragma unroll
      for (int k=0;k<3;k++) {
        const int n = n0 + snl[k];
        regs[k] = *(const float4*)(xb + cpo[k] + (size_t)(n>>6)*8*IMG + (n&63)*8);
      }
    }
    const float* tb = &tile[cur][0][0];
#pragma unroll 4
    for (int nl = nlo; nl < nhi; nl++) {
      const float* tr = tb + nl*JD;
      const float2 a01 = *(const float2*)(tr + r0);
      const float2 a23 = *(const float2*)(tr + r0+2);
      const float2 a45 = *(const float2*)(tr + r0+4);
      const float2 b01 = *(const float2*)(tr + c0);
      const float2 b23 = *(const float2*)(tr + c0+2);
      const float2 b45 = *(const float2*)(tr + c0+4);
      const float va[6] = {a01.x,a01.y,a23.x,a23.y,a45.x,a45.y};
      const float vb[6] = {b01.x,b01.y,b23.x,b23.y,b45.x,b45.y};
#pragma unroll
      for (int i=0;i<6;i++)
#pragma unroll
        for (int j=0;j<6;j++) acc[i][j] += va[i]*vb[j];
    }
    if (it < 31) {
#pragma unroll
      for (int k=0;k<3;k++) *(float4*)(wp0[k] + (cur^1)*6144) = regs[k];
    }
    __syncthreads();
    cur ^= 1;
  }
  if (g == 1) {
#pragma unroll
    for (int i=0;i<6;i++)
#pragma unroll
      for (int j=0;j<6;j++) pacc[tid*37 + i*6+j] = acc[i][j];
  }
  __syncthreads();
  if (g == 0) {
    float* dst = part + (((size_t)(b*4 + sl))*4 + ck) * (size_t)(48*JD);
#pragma unroll
    for (int i=0;i<6;i++)
#pragma unroll
      for (int j=0;j<6;j++)
        dst[(ty*6+i)*JD + c0+j] = acc[i][j] + pacc[tid*37 + i*6+j];
  }
}

// ---------------------------------------------------------------------------
// K2: reduce 4 chunk-partials -> Gs = G / 4096
// ---------------------------------------------------------------------------
__global__ __launch_bounds__(256) void k_greduce(const float* __restrict__ part,
                                                 float* __restrict__ Gs) {
  const int idx = blockIdx.x*256 + threadIdx.x;
  const int b = idx / (JD*JD);
  const int e = idx - b*(JD*JD);
  const int r = e / JD;
  const int sl = r / 48;
  const int w = (r - sl*48)*JD + (e - r*JD);
  const float* p = part + ((size_t)(b*4+sl))*4*(48*JD) + w;
  float s = 0.f;
#pragma unroll
  for (int ck=0; ck<4; ck++) s += p[(size_t)ck*48*JD];
  Gs[idx] = s * (1.0f/4096.0f);
}

// ---------------------------------------------------------------------------
// K3: D = S*S for symmetric S, lower-tri tile pairs. 256 thr.
// float4 staging + double-buffered tiles + issue-early/write-late (r10 recipe).
// ---------------------------------------------------------------------------
__global__ __launch_bounds__(256) void k_sq(const float* __restrict__ S,
                                            float* __restrict__ D) {
  const int tp = blockIdx.x;
  const int b  = blockIdx.y;
  int ti, tj;
  if      (tp==0){ti=0;tj=0;} else if (tp==1){ti=1;tj=0;}
  else if (tp==2){ti=1;tj=1;} else if (tp==3){ti=2;tj=0;}
  else if (tp==4){ti=2;tj=1;} else            {ti=2;tj=2;}
  const float* Sb = S + (size_t)b*JD*JD;
  float* Db = D + (size_t)b*JD*JD;
  __shared__ float Ar[2][64][33];
  __shared__ float Br[2][64][33];
  const int t = threadIdx.x;
  const int ty = t >> 4, tx = t & 15;
  // staging slots: float4 v = t + 256k -> row = v>>3, c4 = v&7
  const int row0 = t >> 3,        c40 = t & 7;
  const int row1 = (t+256) >> 3,  c41 = (t+256) & 7;
  const float* Sa = Sb + (size_t)(ti*64)*JD;
  const float* Sc = Sb + (size_t)(tj*64)*JD;
  float4 ra0, ra1, rb0, rb1;
  auto stage_write = [&](int buf) {
    float* a0 = &Ar[buf][row0][c40*4];
    a0[0]=ra0.x; a0[1]=ra0.y; a0[2]=ra0.z; a0[3]=ra0.w;
    float* a1 = &Ar[buf][row1][c41*4];
    a1[0]=ra1.x; a1[1]=ra1.y; a1[2]=ra1.z; a1[3]=ra1.w;
    float* b0 = &Br[buf][row0][c40*4];
    b0[0]=rb0.x; b0[1]=rb0.y; b0[2]=rb0.z; b0[3]=rb0.w;
    float* b1 = &Br[buf][row1][c41*4];
    b1[0]=rb1.x; b1[1]=rb1.y; b1[2]=rb1.z; b1[3]=rb1.w;
  };
  // prologue: stage k0=0
  ra0 = *(const float4*)(Sa + (size_t)row0*JD + c40*4);
  ra1 = *(const float4*)(Sa + (size_t)row1*JD + c41*4);
  rb0 = *(const float4*)(Sc + (size_t)row0*JD + c40*4);
  rb1 = *(const float4*)(Sc + (size_t)row1*JD + c41*4);
  stage_write(0);
  __syncthreads();

  float acc[4][4];
#pragma unroll
  for (int i=0;i<4;i++)
#pragma unroll
    for (int j=0;j<4;j++) acc[i][j]=0.f;
  int cur = 0;
  for (int s=0; s<6; s++) {
    if (s < 5) {
      const int k0 = (s+1)*32;
      ra0 = *(const float4*)(Sa + (size_t)row0*JD + k0 + c40*4);
      ra1 = *(const float4*)(Sa + (size_t)row1*JD + k0 + c41*4);
      rb0 = *(const float4*)(Sc + (size_t)row0*JD + k0 + c40*4);
      rb1 = *(const float4*)(Sc + (size_t)row1*JD + k0 + c41*4);
    }
#pragma unroll 4
    for (int k=0;k<32;k++) {
      float va[4], vb[4];
#pragma unroll
      for (int i=0;i<4;i++) va[i] = Ar[cur][ty*4+i][k];
#pragma unroll
      for (int j=0;j<4;j++) vb[j] = Br[cur][tx*4+j][k];
#pragma unroll
      for (int i=0;i<4;i++)
#pragma unroll
        for (int j=0;j<4;j++) acc[i][j] += va[i]*vb[j];
    }
    if (s < 5) stage_write(cur^1);
    __syncthreads();
    cur ^= 1;
  }
#pragma unroll
  for (int i=0;i<4;i++)
#pragma unroll
    for (int j=0;j<4;j++) {
      const int r = ti*64+ty*4+i, c = tj*64+tx*4+j;
      Db[r*JD+c] = acc[i][j];
      if (ti != tj) Db[c*JD+r] = acc[i][j];
    }
}

// ---------------------------------------------------------------------------
// LDS-resident helpers for k_subH (512 threads). W: 192 rows, stride 68.
// ---------------------------------------------------------------------------
__device__ void orth_lds(float* __restrict__ Wl, float* __restrict__ Wpart,
                         float* __restrict__ S1,
                         float* __restrict__ rdv, float* __restrict__ pdv,
                         float* __restrict__ misc, int t, float ridge) {
  const int g = t >> 8;
  const int tid = t & 255;
  const int ty = tid >> 4, tx = tid & 15;
  float acc[4][4];
#pragma unroll
  for (int i=0;i<4;i++)
#pragma unroll
    for (int j=0;j<4;j++) acc[i][j]=0.f;
  __syncthreads();
  {
    const int rbeg = g*96;
#pragma unroll 2
    for (int r=rbeg; r<rbeg+96; r++) {
      const float4 va4 = *(const float4*)(Wl + r*68 + ty*4);
      const float4 vb4 = *(const float4*)(Wl + r*68 + tx*4);
      const float a4[4] = {va4.x, va4.y, va4.z, va4.w};
      const float b4[4] = {vb4.x, vb4.y, vb4.z, vb4.w};
#pragma unroll
      for (int i=0;i<4;i++)
#pragma unroll
        for (int j=0;j<4;j++) acc[i][j] += a4[i]*b4[j];
    }
  }
  if (g == 1) {
#pragma unroll
    for (int i=0;i<4;i++)
#pragma unroll
      for (int j=0;j<4;j++)
        Wpart[(ty*4+i)*68 + tx*4+j] = acc[i][j];
  }
  __syncthreads();
  if (g == 0) {
#pragma unroll
    for (int i=0;i<4;i++)
#pragma unroll
      for (int j=0;j<4;j++)
        S1[(ty*4+i)*68 + tx*4+j] = acc[i][j] + Wpart[(ty*4+i)*68 + tx*4+j];
  }
  __syncthreads();
  if (ridge > 0.f) {
    if (t < 64) {
      float d = S1[t*68+t];
#pragma unroll
      for (int o=1;o<64;o<<=1) d = fmaxf(d, __shfl_xor(d, o));
      if (t == 0) misc[0] = d * ridge;
    }
    __syncthreads();
    if (t < 64) S1[t*68+t] += misc[0];
    __syncthreads();
  }
  for (int p=0; p<4; p++) {
    const int b16 = p*16;
    if (t < 64) {
      for (int jj=0; jj<16; jj++) {
        const int j = b16 + jj;
        const float invd = fast_rcp(S1[j*68+j]);
        if (t == 0) pdv[jj] = invd;
        const int nit = (15-jj)*16;
        for (int f=t; f<nit; f+=64) {
          const int i = j+1 + (f>>4);
          const int k = j+1 + (f&15);
          if (k <= i)
            S1[i*68+k] -= S1[i*68+j]*S1[k*68+j]*invd;
        }
      }
    }
    __syncthreads();
    const int rb = b16 + 16;
    if (t < 64 - rb) {
      const int r = rb + t;
      float pr[16];
      float4* prp = (float4*)pr;
      prp[0] = *(const float4*)(S1 + r*68 + b16);
      prp[1] = *(const float4*)(S1 + r*68 + b16 + 4);
      prp[2] = *(const float4*)(S1 + r*68 + b16 + 8);
      prp[3] = *(const float4*)(S1 + r*68 + b16 + 12);
#pragma unroll
      for (int c=1; c<16; c++) {
        float s = pr[c];
#pragma unroll
        for (int j=0; j<c; j++) s -= pr[j]*S1[(b16+c)*68 + b16+j]*pdv[j];
        pr[c] = s;
      }
      *(float4*)(S1 + r*68 + b16)      = prp[0];
      *(float4*)(S1 + r*68 + b16 + 4)  = prp[1];
      *(float4*)(S1 + r*68 + b16 + 8)  = prp[2];
      *(float4*)(S1 + r*68 + b16 + 12) = prp[3];
    }
    __syncthreads();
    for (int f=t; f<2304; f+=512) {
      const int i = rb + f/48;
      const int k = rb + (f - (f/48)*48);
      if (i < 64 && k < 64 && k <= i) {
        float s = S1[i*68+k];
#pragma unroll
        for (int jj=0; jj<16; jj++)
          s -= S1[i*68 + b16+jj]*S1[k*68 + b16+jj]*pdv[jj];
        S1[i*68+k] = s;
      }
    }
    __syncthreads();
  }
  if (t < 64) rdv[t] = rsqrtf(S1[t*68+t]);
  __syncthreads();
  for (int f=t; f<4096; f+=512) {
    const int i = f>>6, k = f&63;
    if (k < i) S1[i*68+k] *= rdv[k];
  }
  __syncthreads();
  if (t < JD) {
    float w[64];
    float4* wp = (float4*)w;
#pragma unroll
    for (int c4=0;c4<16;c4++) wp[c4] = *(const float4*)(Wl + t*68 + c4*4);
#pragma unroll
    for (int c=0;c<64;c++) {
      float v = w[c];
#pragma unroll
      for (int k=0;k<c;k++) v -= w[k]*S1[c*68+k];
      w[c] = v * rdv[c];
    }
#pragma unroll
    for (int c4=0;c4<16;c4++) *(float4*)(Wl + t*68 + c4*4) = wp[c4];
  }
  __syncthreads();
}

__device__ void mm_lds(const float* __restrict__ G, const float* __restrict__ Win,
                       float* __restrict__ Wout, float* __restrict__ Gt, int t) {
  const int rg = t >> 3;
  const int cg = t & 7;
  float acc[4][8];
#pragma unroll
  for (int i=0;i<4;i++)
#pragma unroll
    for (int j=0;j<8;j++) acc[i][j]=0.f;
  for (int k0=0; k0<JD; k0+=32) {
    __syncthreads();
    for (int f=t; f<6144; f+=512) {
      const int kk = f / 192, r = f - kk*192;
      Gt[kk*196 + r] = G[r*JD + k0 + kk];
    }
    __syncthreads();
    if (t < 384) {
#pragma unroll 2
      for (int k=0;k<32;k++) {
        const float4 g4 = *(const float4*)(Gt + k*196 + rg*4);
        const float* wr = Win + (k0+k)*68 + cg*8;
        const float4 w0 = *(const float4*)(wr);
        const float4 w1 = *(const float4*)(wr + 4);
        const float ga[4] = {g4.x, g4.y, g4.z, g4.w};
        const float wb[8] = {w0.x,w0.y,w0.z,w0.w,w1.x,w1.y,w1.z,w1.w};
#pragma unroll
        for (int i=0;i<4;i++)
#pragma unroll
          for (int j=0;j<8;j++) acc[i][j] += ga[i]*wb[j];
      }
    }
  }
  __syncthreads();
  if (t < 384) {
#pragma unroll
    for (int i=0;i<4;i++)
#pragma unroll
      for (int j=0;j<8;j++)
        Wout[(rg*4+i)*68 + cg*8 + j] = acc[i][j];
  }
  __syncthreads();
}

__device__ void hgemm_lds(const float* __restrict__ X, const float* __restrict__ Y,
                          float* __restrict__ S1, int ss, int t) {
  const int ty = t >> 5, tx = t & 31;
  float acc[4][2];
#pragma unroll
  for (int i=0;i<4;i++)
#pragma unroll
    for (int j=0;j<2;j++) acc[i][j]=0.f;
#pragma unroll 2
  for (int r=0; r<JD; r++) {
    const float4 va4 = *(const float4*)(X + r*68 + ty*4);
    const float2 vb2 = *(const float2*)(Y + r*68 + tx*2);
    const float a4[4] = {va4.x, va4.y, va4.z, va4.w};
    const float b2[2] = {vb2.x, vb2.y};
#pragma unroll
    for (int i=0;i<4;i++)
#pragma unroll
      for (int j=0;j<2;j++) acc[i][j] += a4[i]*b2[j];
  }
  __syncthreads();
#pragma unroll
  for (int i=0;i<4;i++)
#pragma unroll
    for (int j=0;j<2;j++)
      S1[(ty*4+i)*ss + tx*2+j] = acc[i][j];
  __syncthreads();
}

// ---------------------------------------------------------------------------
// K4a: subspace basis + H, all W traffic in LDS. grid 16, 512 thr.
// ---------------------------------------------------------------------------
__global__ __launch_bounds__(512) void k_subH(const float* __restrict__ G32g,
                                              const float* __restrict__ Gsg,
                                              float* __restrict__ WbG,
                                              float* __restrict__ Hgg) {
  const int b = blockIdx.x;
  const int t = threadIdx.x;
  __shared__ __align__(16) float W0l[192*68];
  __shared__ __align__(16) float W1l[192*68];
  __shared__ __align__(16) float scr[32*196];
  __shared__ float rdv[64];
  __shared__ float pdv[16];
  __shared__ float misc[8];
  const float* Gb  = G32g + (size_t)b*JD*JD;
  const float* Gsb = Gsg  + (size_t)b*JD*JD;

  for (int f=t; f<JD*64; f+=512)
    W0l[(f>>6)*68 + (f&63)] = Gb[(f>>6)*JD + (f&63)];
  __syncthreads();

  orth_lds(W0l, W1l, scr, rdv, pdv, misc, t, 1e-6f);
  mm_lds(Gb, W0l, W1l, scr, t);
  orth_lds(W1l, W0l, scr, rdv, pdv, misc, t, 1e-6f);
  orth_lds(W1l, W0l, scr, rdv, pdv, misc, t, 0.f);

  mm_lds(Gsb, W1l, W0l, scr, t);
  hgemm_lds(W1l, W0l, scr, 65, t);

  float* Wb = WbG + (size_t)b*JD*64;
  for (int f=t; f<JD*64; f+=512)
    Wb[f] = W1l[(f>>6)*68 + (f&63)];
  float* Hb = Hgg + (size_t)b*4160;
  for (int f=t; f<4160; f+=512) Hb[f] = scr[f];
}

// ---------------------------------------------------------------------------
// Householder tridiag of A (64x64, stride 65) in place (256-thread update).
// ---------------------------------------------------------------------------
__device__ void dev_tridiag(float* __restrict__ A, float* a, float* b2,
                            float* bsg, float* v0s, float* bts,
                            float* vvec, float* wvec, int t) {
  for (int j=0; j<=61; j++) {
    const int m = 63 - j;
    if (t < 64) {
      float xi = (t < m) ? A[j*65 + (j+1+t)] : 0.f;
      float nr = xi*xi;
#pragma unroll
      for (int o=1;o<64;o<<=1) nr += __shfl_xor(nr, o);
      const float sig = sqrtf(nr);
      const float alpha = __shfl(xi, 0);
      const float sgn = (alpha >= 0.f) ? 1.f : -1.f;
      const float v0 = alpha + sgn*sig;
      const float beta = (sig > 1e-20f) ? 1.0f/(sig*fabsf(v0)) : 0.f;
      if (t < m) vvec[t] = (t==0) ? v0 : xi;
      if (t == 0) {
        a[j] = A[j*65+j]; b2[j] = nr; bsg[j] = -sgn*sig;
        v0s[j] = v0; bts[j] = beta;
      }
      float pv = 0.f;
      if (t < m) {
        const float* row = A + (j+1+t)*65 + (j+1);
        for (int c=0;c<m;c++) pv += row[c]*vvec[c];
        pv *= beta;
      }
      float dp = (t<m) ? vvec[t]*pv : 0.f;
#pragma unroll
      for (int o=1;o<64;o<<=1) dp += __shfl_xor(dp, o);
      const float gamma = 0.5f*beta*dp;
      if (t < m) wvec[t] = pv - gamma*vvec[t];
    }
    __syncthreads();
    const int mm = m*m;
    for (int f=t; f<mm; f+=256) {
      const int r = f/m, c = f - r*m;
      A[(j+1+r)*65 + (j+1+c)] -= vvec[r]*wvec[c] + wvec[r]*vvec[c];
    }
    __syncthreads();
  }
  if (t == 0) {
    a[62] = A[62*65+62];
    a[63] = A[63*65+63];
    const float bb = A[62*65+63];
    b2[62] = bb*bb;
    bsg[62] = bb;
  }
  __syncthreads();
}

// Sturm count with fast reciprocal
__device__ inline int sturm_cnt_fast(const float* a, const float* b2, float sig) {
  float d = a[0] - sig;
  int n = (d < 0.f) ? 1 : 0;
#pragma unroll 8
  for (int i=1;i<64;i++) {
    const float dd = (fabsf(d) < 1e-20f) ? -1e-20f : d;
    d = (a[i]-sig) - b2[i-1]*fast_rcp(dd);
    n += (d < 0.f) ? 1 : 0;
  }
  return n;
}

__device__ inline float dguard(float d) {
  if (fabsf(d) < 1e-12f) return (d < 0.f) ? -1e-12f : 1e-12f;
  return d;
}

// ---------------------------------------------------------------------------
// K4b: tridiag + eigenvalues + twisted + CholQR32 + backtransform + B=W*V,
// fused. grid 16, 256 thr. Outputs Btg (32x192 per batch).
// ---------------------------------------------------------------------------
__global__ __launch_bounds__(256) void k_eigv(const float* __restrict__ Hgg,
                                              const float* __restrict__ WbG,
                                              float* __restrict__ Btg) {
  const int b = blockIdx.x;
  const int t = threadIdx.x;
  __shared__ float SH[4160];
  __shared__ float Vt[64*36];
  __shared__ float dpA[64*33];
  __shared__ float dmA[64*33];
  __shared__ float ps[8*33];
  __shared__ float wvred[32];
  __shared__ float rdv[64];
  __shared__ float a64[64];
  __shared__ float b2v[64];
  __shared__ float bsg[64];
  __shared__ float v0s[64];
  __shared__ float bts[64];
  __shared__ float vvec[64];
  __shared__ float wvec[64];
  __shared__ float lam[32];
  __shared__ float misc[8];
  const float* Hb = Hgg + (size_t)b*4160;
  for (int f=t; f<4160; f+=256) SH[f] = Hb[f];
  __syncthreads();

  dev_tridiag(SH, a64, b2v, bsg, v0s, bts, vvec, wvec, t);

  // ---- spectrum bounds (Gershgorin) ----
  if (t < 64) {
    const float bl = (t>0)  ? sqrtf(b2v[t-1]) : 0.f;
    const float br = (t<63) ? sqrtf(b2v[t])   : 0.f;
    float lo = a64[t] - bl - br, hi = a64[t] + bl + br;
#pragma unroll
    for (int o=1;o<64;o<<=1) {
      lo = fminf(lo, __shfl_xor(lo,o));
      hi = fmaxf(hi, __shfl_xor(hi,o));
    }
    if (t == 0) { misc[0] = lo - 1e-4f; misc[1] = hi + 1e-4f; }
  }
  __syncthreads();

  // ---- 9-section search ----
  {
    const int l = t >> 3, g = t & 7;
    const int r = 32 + l;
    float L = misc[0], H = misc[1];
    for (int it=0; it<10; it++) {
      const float mid = L + (H-L)*((float)(g+1)*(1.0f/9.0f));
      const int cnt = sturm_cnt_fast(a64, b2v, mid);
      float nL = L, nH = H;
#pragma unroll
      for (int k=0;k<8;k++) {
        const int ck = __shfl(cnt, k, 8);
        const float pk = L + (H-L)*((float)(k+1)*(1.0f/9.0f));
        if (ck <= r) nL = fmaxf(nL, pk); else nH = fminf(nH, pk);
      }
      L = nL; H = nH;
    }
    if (g == 0) lam[l] = 0.5f*(L+H);
  }
  __syncthreads();

  // ---- twisted-factorization inverse iteration ----
  if (t < 32) {
    const int l = t;
    const float lm = lam[l];
    float d = dguard(a64[0] - lm);
    dpA[0*33+l] = d;
    for (int i=1;i<64;i++) {
      d = dguard((a64[i]-lm) - b2v[i-1]*fast_rcp(d));
      dpA[i*33+l] = d;
    }
    float e = dguard(a64[63] - lm);
    dmA[63*33+l] = e;
    for (int i=62;i>=0;i--) {
      e = dguard((a64[i]-lm) - b2v[i]*fast_rcp(e));
      dmA[i*33+l] = e;
    }
    int ks = 0; float gbest = 1e30f;
    for (int i=0;i<64;i++) {
      const float g = fabsf(dpA[i*33+l] + dmA[i*33+l] - (a64[i]-lm));
      if (g < gbest) { gbest = g; ks = i; }
    }
    Vt[ks*36+l] = 1.f;
    float z = 1.f;
    for (int i=ks-1;i>=0;i--) {
      z = -(bsg[i]*z) * fast_rcp(dpA[i*33+l]);
      z = fminf(fmaxf(z, -1e18f), 1e18f);
      Vt[i*36+l] = z;
    }
    z = 1.f;
    for (int i=ks+1;i<64;i++) {
      z = -(bsg[i-1]*z) * fast_rcp(dmA[i*33+l]);
      z = fminf(fmaxf(z, -1e18f), 1e18f);
      Vt[i*36+l] = z;
    }
    float nr2 = 0.f;
    for (int i=0;i<64;i++) { const float zz = Vt[i*36+l]; nr2 += zz*zz; }
    const float inv = rsqrtf(nr2);
    for (int i=0;i<64;i++) Vt[i*36+l] *= inv;
  }
  __syncthreads();

  // ---- CholQR-32 safety pass on Vt ----
  for (int f=t; f<1024; f+=256) {
    const int i = f>>5, j = f&31;
    float s = 0.f;
    for (int r=0;r<64;r++) s += Vt[r*36+i]*Vt[r*36+j];
    dpA[i*33+j] = s;
  }
  __syncthreads();
  if (t == 0) {
    float m = 0.f;
    for (int j=0;j<32;j++) m = fmaxf(m, dpA[j*33+j]);
    misc[2] = m * 1e-7f;
  }
  __syncthreads();
  if (t < 32) dpA[t*33+t] += misc[2];
  for (int j=0;j<31;j++) {
    __syncthreads();
    const float invd = fast_rcp(dpA[j*33+j]);
    for (int f=t; f<(31-j)*32; f+=256) {
      const int i = j+1 + (f>>5);
      const int k = f & 31;
      if (k > j && k <= i)
        dpA[i*33+k] -= dpA[i*33+j]*dpA[k*33+j]*invd;
    }
  }
  __syncthreads();
  if (t < 32) rdv[t] = rsqrtf(dpA[t*33+t]);
  __syncthreads();
  for (int f=t; f<1024; f+=256) {
    const int i = f>>5, k = f&31;
    if (k < i) dpA[i*33+k] *= rdv[k];
  }
  __syncthreads();
  if (t < 64) {
    float w[32];
#pragma unroll
    for (int c=0;c<32;c++) w[c] = Vt[t*36+c];
#pragma unroll
    for (int c=0;c<32;c++) {
      float v = w[c];
#pragma unroll
      for (int k=0;k<c;k++) v -= w[k]*dpA[c*33+k];
      w[c] = v * rdv[c];
    }
#pragma unroll
    for (int c=0;c<32;c++) Vt[t*36+c] = w[c];
  }
  __syncthreads();

  // ---- backtransform: V = H_0 H_1 ... H_61 Vt ----
  for (int j=61; j>=0; j--) {
    const int m = 63 - j;
    {
      const int c = t & 31, g = t >> 5;
      float s = 0.f;
      for (int r=g; r<m; r+=8) {
        const float vr = (r==0) ? v0s[j] : SH[j*65 + (j+1+r)];
        s += vr * Vt[(j+1+r)*36 + c];
      }
      ps[g*33+c] = s;
    }
    __syncthreads();
    if (t < 32) {
      float s = 0.f;
#pragma unroll
      for (int g=0;g<8;g++) s += ps[g*33+t];
      wvred[t] = s * bts[j];
    }
    __syncthreads();
    {
      const int c = t & 31, g = t >> 5;
      for (int r=g; r<m; r+=8) {
        const float vr = (r==0) ? v0s[j] : SH[j*65 + (j+1+r)];
        Vt[(j+1+r)*36 + c] -= vr * wvred[c];
      }
    }
    __syncthreads();
  }

  // ---- fused B^T = (W * V)^T -> Btg (32 x 192 row-major) ----
  const float* W = WbG + (size_t)b*JD*64;
  float* Bt = Btg + (size_t)b*32*JD;
  if (t < JD) {
    float accv[32];
#pragma unroll
    for (int c=0;c<32;c++) accv[c] = 0.f;
    const float4* crow = (const float4*)(W + t*64);
#pragma unroll 2
    for (int kb=0; kb<16; kb++) {
      const float4 av = crow[kb];
      const float a4[4] = {av.x, av.y, av.z, av.w};
#pragma unroll
      for (int ki=0; ki<4; ki++) {
        const float aa = a4[ki];
        const float* vrow = Vt + (kb*4+ki)*36;
        const float4 v0 = *(const float4*)(vrow+0);
        const float4 v1 = *(const float4*)(vrow+4);
        const float4 v2 = *(const float4*)(vrow+8);
        const float4 v3 = *(const float4*)(vrow+12);
        const float4 v4 = *(const float4*)(vrow+16);
        const float4 v5 = *(const float4*)(vrow+20);
        const float4 v6 = *(const float4*)(vrow+24);
        const float4 v7 = *(const float4*)(vrow+28);
        accv[0]+=aa*v0.x; accv[1]+=aa*v0.y; accv[2]+=aa*v0.z; accv[3]+=aa*v0.w;
        accv[4]+=aa*v1.x; accv[5]+=aa*v1.y; accv[6]+=aa*v1.z; accv[7]+=aa*v1.w;
        accv[8]+=aa*v2.x; accv[9]+=aa*v2.y; accv[10]+=aa*v2.z; accv[11]+=aa*v2.w;
        accv[12]+=aa*v3.x; accv[13]+=aa*v3.y; accv[14]+=aa*v3.z; accv[15]+=aa*v3.w;
        accv[16]+=aa*v4.x; accv[17]+=aa*v4.y; accv[18]+=aa*v4.z; accv[19]+=aa*v4.w;
        accv[20]+=aa*v5.x; accv[21]+=aa*v5.y; accv[22]+=aa*v5.z; accv[23]+=aa*v5.w;
        accv[24]+=aa*v6.x; accv[25]+=aa*v6.y; accv[26]+=aa*v6.z; accv[27]+=aa*v6.w;
        accv[28]+=aa*v7.x; accv[29]+=aa*v7.y; accv[30]+=aa*v7.z; accv[31]+=aa*v7.w;
      }
    }
#pragma unroll
    for (int c=0;c<32;c++) Bt[c*JD + t] = accv[c];
  }
}

// ---------------------------------------------------------------------------
// K4d: M = B B^T = Bt^T Bt, lower-tri tile pairs. grid (6,16).
// ---------------------------------------------------------------------------
__global__ __launch_bounds__(256) void k_mm(const float* __restrict__ Btg,
                                            float* __restrict__ Mg) {
  const int tp = blockIdx.x;
  const int b  = blockIdx.y;
  int ti, tj;
  if      (tp==0){ti=0;tj=0;} else if (tp==1){ti=1;tj=0;}
  else if (tp==2){ti=1;tj=1;} else if (tp==3){ti=2;tj=0;}
  else if (tp==4){ti=2;tj=1;} else            {ti=2;tj=2;}
  const float* Bt = Btg + (size_t)b*32*JD;
  float* Mb = Mg + (size_t)b*JD*JD;
  __shared__ float Ar[32][68];
  __shared__ float Br[32][68];
  const int t = threadIdx.x;
  const int ty = t >> 4, tx = t & 15;
  for (int f=t; f<2048; f+=256) {
    const int k = f >> 6, c = f & 63;
    Ar[k][c] = Bt[k*JD + ti*64 + c];
    Br[k][c] = Bt[k*JD + tj*64 + c];
  }
  __syncthreads();
  float acc[4][4];
#pragma unroll
  for (int i=0;i<4;i++)
#pragma unroll
    for (int j=0;j<4;j++) acc[i][j]=0.f;
#pragma unroll 4
  for (int k=0;k<32;k++) {
    const float4 va4 = *(const float4*)(&Ar[k][ty*4]);
    const float4 vb4 = *(const float4*)(&Br[k][tx*4]);
    const float a4[4] = {va4.x, va4.y, va4.z, va4.w};
    const float b4[4] = {vb4.x, vb4.y, vb4.z, vb4.w};
#pragma unroll
    for (int i=0;i<4;i++)
#pragma unroll
      for (int j=0;j<4;j++) acc[i][j] += a4[i]*b4[j];
  }
#pragma unroll
  for (int i=0;i<4;i++)
#pragma unroll
    for (int j=0;j<4;j++) {
      const int r = ti*64+ty*4+i, c = tj*64+tx*4+j;
      Mb[r*JD+c] = acc[i][j];
      if (ti != tj) Mb[c*JD+r] = acc[i][j];
    }
}

// ---------------------------------------------------------------------------
// K5: recon = A * M, fused depatchify. grid (128 patch-blocks, 16 batches).
// ---------------------------------------------------------------------------
__global__ __launch_bounds__(256) void k_recon(const float* __restrict__ x,
                                               const float* __restrict__ Mg,
                                               float* __restrict__ out) {
  const int nb = blockIdx.x;
  const int b  = blockIdx.y;
  const int t  = threadIdx.x;
  __shared__ float At[32][17];
  __shared__ float Mt[16][JD];
  const float* xb = x + (size_t)b*3*IMG*IMG;
  const float* Mb = Mg + (size_t)b*JD*JD;
  float* ob = out + (size_t)b*3*IMG*IMG;
  const int pg = t >> 4;
  const int jg = t & 15;
  float acc[2][12];
#pragma unroll
  for (int i=0;i<2;i++)
#pragma unroll
    for (int j=0;j<12;j++) acc[i][j]=0.f;
  for (int j0=0; j0<JD; j0+=16) {
    for (int f=t; f<512; f+=256) {
      const int nl = f >> 4, jj = f & 15;
      const int j = j0 + jj;
      const int n = nb*32 + nl;
      const int hh = n >> 6, ww = n & 63;
      const int c = j >> 6, p = (j >> 3) & 7, q = j & 7;
      At[nl][jj] = xb[(c*IMG + hh*8+p)*IMG + ww*8 + q];
    }
    for (int f=t; f<768; f+=256) {
      const int jj = f/48, cc = (f - jj*48)*4;
      *(float4*)(&Mt[jj][cc]) = *(const float4*)(Mb + (size_t)(j0+jj)*JD + cc);
    }
    __syncthreads();
#pragma unroll 4
    for (int jj=0;jj<16;jj++) {
      const float a0 = At[pg*2+0][jj];
      const float a1 = At[pg*2+1][jj];
      const float4 m0 = *(const float4*)(&Mt[jj][jg*12]);
      const float4 m1 = *(const float4*)(&Mt[jj][jg*12+4]);
      const float4 m2 = *(const float4*)(&Mt[jj][jg*12+8]);
      const float mm[12] = {m0.x,m0.y,m0.z,m0.w,m1.x,m1.y,m1.z,m1.w,
                            m2.x,m2.y,m2.z,m2.w};
#pragma unroll
      for (int j=0;j<12;j++) {
        acc[0][j] += a0*mm[j];
        acc[1][j] += a1*mm[j];
      }
    }
    __syncthreads();
  }
#pragma unroll
  for (int i=0;i<2;i++) {
    const int n = nb*32 + pg*2 + i;
    const int hh = n >> 6, ww = n & 63;
#pragma unroll
    for (int j4=0;j4<3;j4++) {
      const int jo = jg*12 + j4*4;
      const int c = jo >> 6, p = (jo >> 3) & 7, q = jo & 7;
      const float4 v = make_float4(acc[i][j4*4+0], acc[i][j4*4+1],
                                   acc[i][j4*4+2], acc[i][j4*4+3]);
      *(float4*)(ob + (size_t)(c*IMG + hh*8+p)*IMG + ww*8 + q) = v;
    }
  }
}

// ---------------------------------------------------------------------------
extern "C" void kernel_launch(void* const* d_in, const int* in_sizes, int n_in,
                              void* d_out, int out_size, void* d_ws, size_t ws_size,
                              hipStream_t stream) {
  (void)in_sizes; (void)n_in; (void)out_size; (void)ws_size;
  const float* x = (const float*)d_in[0];
  float* out = (float*)d_out;
  float* ws  = (float*)d_ws;

  float* part = ws;                    // dead after k_greduce
  float* Gs   = ws + 2359296;
  float* P0   = ws + 2949120;
  float* P1   = ws + 3538944;
  // overlays on the (dead) part region:
  float* Mg   = ws;                    // 589824
  float* Wb   = ws + 786432;           // 196608
  float* Hg   = ws + 983040;           // 66560 (64x65 per batch)
  float* Btg  = ws + 1090560;          // 98304 (32x192 per batch)

  k_gram  <<<dim3(4,4,16), 512, 0, stream>>>(x, part);
  k_greduce<<<2304,        256, 0, stream>>>(part, Gs);
  k_sq    <<<dim3(6,16),   256, 0, stream>>>(Gs, P0);   // Gs^2
  k_sq    <<<dim3(6,16),   256, 0, stream>>>(P0, P1);   // Gs^4
  k_sq    <<<dim3(6,16),   256, 0, stream>>>(P1, P0);   // Gs^8
  k_sq    <<<dim3(6,16),   256, 0, stream>>>(P0, P1);   // Gs^16
  k_sq    <<<dim3(6,16),   256, 0, stream>>>(P1, P0);   // Gs^32
  k_subH  <<<16,           512, 0, stream>>>(P0, Gs, Wb, Hg);
  k_eigv  <<<16,           256, 0, stream>>>(Hg, Wb, Btg);
  k_mm    <<<dim3(6,16),   256, 0, stream>>>(Btg, Mg);
  k_recon <<<dim3(128,16), 256, 0, stream>>>(x, Mg, out);
}